// Round 4
// baseline (5327.030 us; speedup 1.0000x reference)
//
#include <hip/hip_runtime.h>
#include <hip/hip_bf16.h>

typedef __attribute__((ext_vector_type(8))) short short8;
typedef __attribute__((ext_vector_type(4))) float f32x4;
typedef __attribute__((ext_vector_type(4))) int i32x4;

#define SEQ   256   // source length S
#define BB    16    // batch
#define EE    256   // embed dim
#define HH    256   // hidden
#define GG    1024  // 4*H
#define TT    128   // target_size
#define NWG   32    // persistent workgroups
#define KP    264   // LDS row stride in shorts (breaks 512B-stride bank conflicts)

__device__ __forceinline__ float sigm(float x) { return 1.0f / (1.0f + __expf(-x)); }
__device__ __forceinline__ float tanh_f(float x) {
    float e = __expf(2.0f * x);
    return 1.0f - 2.0f / (e + 1.0f);
}
__device__ __forceinline__ void split2s(float v, short* hi, short* lo) {
    __hip_bfloat16 h = __float2bfloat16(v);
    __hip_bfloat16 l = __float2bfloat16(v - __bfloat162float(h));
    *hi = *(short*)&h; *lo = *(short*)&l;
}
__device__ __forceinline__ f32x4 MFMA(short8 a, short8 b, f32x4 c) {
    return __builtin_amdgcn_mfma_f32_16x16x32_bf16(a, b, c, 0, 0, 0);
}

// ---- LLC-coherent access (sc1, bypasses per-XCD L2; no cache-maintenance ops) ----
__device__ __forceinline__ int ld_a(const int* p) {
    return __hip_atomic_load(p, __ATOMIC_RELAXED, __HIP_MEMORY_SCOPE_AGENT);
}
__device__ __forceinline__ void st_a(int* p, int v) {
    __hip_atomic_store(p, v, __ATOMIC_RELAXED, __HIP_MEMORY_SCOPE_AGENT);
}
__device__ __forceinline__ short8 ld_frag(const short* p) {
    const int* q = (const int*)p;
    i32x4 r;
    r.x = ld_a(q); r.y = ld_a(q + 1); r.z = ld_a(q + 2); r.w = ld_a(q + 3);
    return *(short8*)&r;
}

// ---- grid barrier: flag-array, relaxed agent atomics; __syncthreads drains vmcnt ----
__device__ __forceinline__ void gbar(int* flags, int target) {
    __syncthreads();   // compiler emits s_waitcnt vmcnt(0) before s_barrier: stores done
    if (threadIdx.x == 0)
        st_a(&flags[blockIdx.x], target);
    if (threadIdx.x < 64) {
        int i = threadIdx.x & 31;
        while (ld_a(&flags[i]) < target) __builtin_amdgcn_s_sleep(1);
    }
    asm volatile("" ::: "memory");
    __syncthreads();
}

// ---------------- utility kernels ----------------
__global__ void k_binit(int* p) { if (threadIdx.x < 64) p[threadIdx.x] = 0; }

__global__ void k_cvt2(const float* __restrict__ s, __hip_bfloat16* __restrict__ hi,
                       __hip_bfloat16* __restrict__ lo, int n) {
    int i = blockIdx.x * 256 + threadIdx.x;
    if (i < n) {
        short a, b; split2s(s[i], &a, &b);
        hi[i] = *(__hip_bfloat16*)&a; lo[i] = *(__hip_bfloat16*)&b;
    }
}

__global__ void k_zero(float* __restrict__ p) {
    p[blockIdx.x * 256 + threadIdx.x] = 0.0f;
}

__global__ void k_embed(const int* __restrict__ src, const float* __restrict__ tab,
                        __hip_bfloat16* __restrict__ xhi, __hip_bfloat16* __restrict__ xlo) {
    int r = blockIdx.x;          // r = t*B + b
    int j = threadIdx.x;
    long idx = src[r];
    short a, b; split2s(tab[idx * EE + j], &a, &b);
    xhi[(long)r * EE + j] = *(__hip_bfloat16*)&a;
    xlo[(long)r * EE + j] = *(__hip_bfloat16*)&b;
}

// ------------- input-side GEMM: gates0 = X @ Wih0^T + bih0 + bhh0 (f32-accurate) -------------
__global__ void __launch_bounds__(256) k_gemm_in(
        const __hip_bfloat16* __restrict__ Xhi, const __hip_bfloat16* __restrict__ Xlo,
        const __hip_bfloat16* __restrict__ Whi, const __hip_bfloat16* __restrict__ Wlo,
        const float* __restrict__ bih, const float* __restrict__ bhh,
        float* __restrict__ gates) {
    int lane = threadIdx.x & 63, w = threadIdx.x >> 6;
    int m0 = (blockIdx.x >> 4) * 16;
    int n0 = ((blockIdx.x & 15) * 4 + w) * 16;
    int cc = lane & 15, g = lane >> 4;
    int koff = g * 8;
    const short* xh = (const short*)Xhi + (long)(m0 + cc) * EE + koff;
    const short* xl = (const short*)Xlo + (long)(m0 + cc) * EE + koff;
    const short* wh = (const short*)Whi + (long)(n0 + cc) * EE + koff;
    const short* wl = (const short*)Wlo + (long)(n0 + cc) * EE + koff;
    f32x4 acc1 = {0.f, 0.f, 0.f, 0.f}, acc2 = {0.f, 0.f, 0.f, 0.f};
#pragma unroll
    for (int k = 0; k < EE; k += 32) {
        short8 ah = *(const short8*)(xh + k), al = *(const short8*)(xl + k);
        short8 bh = *(const short8*)(wh + k), bl = *(const short8*)(wl + k);
        acc1 = MFMA(ah, bh, acc1);
        acc2 = MFMA(ah, bl, acc2);
        acc2 = MFMA(al, bh, acc2);
    }
    f32x4 acc = acc1 + acc2;
    int ncol = n0 + cc;
    float bias = bih[ncol] + bhh[ncol];
    int mrow = m0 + g * 4;
#pragma unroll
    for (int r = 0; r < 4; ++r)
        gates[(long)(mrow + r) * GG + ncol] = acc[r] + bias;
}

// ---- gather one 32-row weight slice (rows q*256+j0+jl -> lr=q*8+jl) into LDS ----
__device__ __forceinline__ void load_wslice(const short* __restrict__ Wg, int j0,
                                            short* __restrict__ Wl) {
    int tid = threadIdx.x;
    int lr = tid >> 3;                 // 0..31
    int q = lr >> 3, jl = lr & 7;
    const short* src = Wg + (long)(q * 256 + j0 + jl) * 256;
    short* dst = Wl + lr * KP;
#pragma unroll
    for (int s = 0; s < 4; ++s) {
        int c = (tid & 7) * 8 + s * 64;
        *(short8*)(dst + c) = *(const short8*)(src + c);
    }
}

// ---------------- encoder: both layers, wavefront (L1 one step behind L0) ----------------
__global__ void __launch_bounds__(256) k_enc_coop(
        const float* __restrict__ gates0,                  // [S*B][G] L0 x-gates + bias
        const short* __restrict__ Whh0h, const short* __restrict__ Whh0l,
        const short* __restrict__ Wih1h, const short* __restrict__ Wih1l,
        const short* __restrict__ Whh1h, const short* __restrict__ Whh1l,
        const float* __restrict__ bih1, const float* __restrict__ bhh1,
        const float* __restrict__ h0p, const float* __restrict__ c0p,  // [2][16][256]
        short* __restrict__ h0bh, short* __restrict__ h0bl,  // [2][4096] double buf
        short* __restrict__ h1bh, short* __restrict__ h1bl,
        float* __restrict__ hfin, int* __restrict__ flags) {
    __shared__ short Wl[6][32 * KP];
    __shared__ float gacc[4][16][17];

    int tid = threadIdx.x;
    int j0 = blockIdx.x * 8;
    load_wslice(Whh0h, j0, Wl[0]); load_wslice(Whh0l, j0, Wl[1]);
    load_wslice(Wih1h, j0, Wl[2]); load_wslice(Wih1l, j0, Wl[3]);
    load_wslice(Whh1h, j0, Wl[4]); load_wslice(Whh1l, j0, Wl[5]);

    int bb = (tid & 127) >> 3, jl = tid & 7, j = j0 + jl, lay = tid >> 7;
    float creg = c0p[lay * 4096 + bb * 256 + j];
    float bs[4] = {0.f, 0.f, 0.f, 0.f};
    if (lay) {
#pragma unroll
        for (int q = 0; q < 4; ++q) bs[q] = bih1[q * 256 + j] + bhh1[q * 256 + j];
    }
    {   // init: L0 state -> buf1 (read at i=0), L1 state -> buf0 (read at i=1)
        float hv = h0p[lay * 4096 + bb * 256 + j];
        short sh, sl; split2s(hv, &sh, &sl);
        int mh = (unsigned short)sh, ml = (unsigned short)sl;
        int nh = __shfl_down(mh, 1), nl = __shfl_down(ml, 1);
        short* dh = lay ? h1bh : (h0bh + 4096);
        short* dl = lay ? h1bl : (h0bl + 4096);
        if (!(jl & 1)) {
            st_a((int*)dh + ((bb * 256 + j) >> 1), mh | (nh << 16));
            st_a((int*)dl + ((bb * 256 + j) >> 1), ml | (nl << 16));
        }
    }
    int gen = 0;
    gbar(flags, ++gen);

    int lane = tid & 63, w = tid >> 6, cc = lane & 15, g4 = lane >> 4, koff = g4 * 8;

    for (int i = 0; i <= SEQ; ++i) {
        int rb = (i + 1) & 1, wb = i & 1;
        bool act = lay ? (i >= 1) : (i < SEQ);
        int t = lay ? (i - 1) : i;
        float gpre[4] = {0.f, 0.f, 0.f, 0.f};
        if (!lay && act) {     // prefetch x-side gates: hides HBM latency under MFMA
#pragma unroll
            for (int q = 0; q < 4; ++q)
                gpre[q] = gates0[(long)(t * BB + bb) * GG + q * 256 + j];
        }
        f32x4 acc1 = {0.f, 0.f, 0.f, 0.f}, acc2 = {0.f, 0.f, 0.f, 0.f};
        if (w < 2) {                       // L0 tile w, full K, A = h0 state
            if (i < SEQ) {
                int aoff = rb * 4096 + cc * 256 + koff;
                int woff = (w * 16 + cc) * KP + koff;
                const short *ah = h0bh + aoff, *al = h0bl + aoff;
#pragma unroll
                for (int k = 0; k < 256; k += 32) {
                    short8 vh = ld_frag(ah + k), vl = ld_frag(al + k);
                    short8 wh = *(const short8*)(Wl[0] + woff + k);
                    short8 wl2 = *(const short8*)(Wl[1] + woff + k);
                    acc1 = MFMA(vh, wh, acc1);
                    acc2 = MFMA(vh, wl2, acc2);
                    acc2 = MFMA(vl, wh, acc2);
                }
            }
        } else if (i >= 1) {               // L1 tile w-2, x = h0(prev), h = h1 state
            int tw = w - 2;
            int aoff = rb * 4096 + cc * 256 + koff;
            int woff = (tw * 16 + cc) * KP + koff;
            const short *xh = h0bh + aoff, *xl = h0bl + aoff;
            const short *hh = h1bh + aoff, *hl = h1bl + aoff;
#pragma unroll
            for (int k = 0; k < 256; k += 32) {
                short8 vxh = ld_frag(xh + k), vxl = ld_frag(xl + k);
                acc1 = MFMA(vxh, *(const short8*)(Wl[2] + woff + k), acc1);
                acc2 = MFMA(vxh, *(const short8*)(Wl[3] + woff + k), acc2);
                acc2 = MFMA(vxl, *(const short8*)(Wl[2] + woff + k), acc2);
                short8 vhh = ld_frag(hh + k), vhl = ld_frag(hl + k);
                acc1 = MFMA(vhh, *(const short8*)(Wl[4] + woff + k), acc1);
                acc2 = MFMA(vhh, *(const short8*)(Wl[5] + woff + k), acc2);
                acc2 = MFMA(vhl, *(const short8*)(Wl[4] + woff + k), acc2);
            }
        }
        f32x4 accs = acc1 + acc2;
#pragma unroll
        for (int r = 0; r < 4; ++r) gacc[w][g4 * 4 + r][cc] = accs[r];
        __syncthreads();

        if (act) {
            float gv[4];
#pragma unroll
            for (int q = 0; q < 4; ++q) {
                int lr = q * 8 + jl;
                float v = gacc[lay * 2 + (lr >> 4)][bb][lr & 15] + bs[q];
                if (!lay) v += gpre[q];
                gv[q] = v;
            }
            float c = sigm(gv[1]) * creg + sigm(gv[0]) * tanh_f(gv[2]);
            creg = c;
            float h = sigm(gv[3]) * tanh_f(c);
            short sh, sl; split2s(h, &sh, &sl);
            int mh = (unsigned short)sh, ml = (unsigned short)sl;
            int nh = __shfl_down(mh, 1), nl = __shfl_down(ml, 1);
            short* dh = (lay ? h1bh : h0bh) + wb * 4096;
            short* dl = (lay ? h1bl : h0bl) + wb * 4096;
            if (!(jl & 1)) {
                st_a((int*)dh + ((bb * 256 + j) >> 1), mh | (nh << 16));
                st_a((int*)dl + ((bb * 256 + j) >> 1), ml | (nl << 16));
            }
            if (t == SEQ - 1) hfin[lay * 4096 + bb * 256 + j] = h;
        }
        gbar(flags, ++gen);
    }
}

// ---------------- decoder: 2 phases/step (L0 then L1), weights LDS-resident ----------------
__global__ void __launch_bounds__(256) k_dec_coop(
        const short* __restrict__ Wihh, const short* __restrict__ Wihl,   // [2][1024][256]
        const short* __restrict__ Whhh, const short* __restrict__ Whhl,
        const float* __restrict__ dbih, const float* __restrict__ dbhh,   // [2][1024]
        const float* __restrict__ tef, const float* __restrict__ hfin,
        short* __restrict__ h0bh, short* __restrict__ h0bl,   // [2][4096]
        short* __restrict__ h1bh, short* __restrict__ h1bl,
        short* __restrict__ teh, short* __restrict__ tel,     // [4096] init bufs
        short* __restrict__ h0ih, short* __restrict__ h0il,
        short* __restrict__ h1ih, short* __restrict__ h1il,
        float* __restrict__ preds, int* __restrict__ flags) {
    __shared__ short Wl[8][32 * KP];
    __shared__ float gacc[4][16][17];
    const int WN = GG * EE;

    int tid = threadIdx.x;
    int j0 = blockIdx.x * 8;
    load_wslice(Wihh, j0, Wl[0]);      load_wslice(Wihl, j0, Wl[1]);
    load_wslice(Whhh, j0, Wl[2]);      load_wslice(Whhl, j0, Wl[3]);
    load_wslice(Wihh + WN, j0, Wl[4]); load_wslice(Wihl + WN, j0, Wl[5]);
    load_wslice(Whhh + WN, j0, Wl[6]); load_wslice(Whhl + WN, j0, Wl[7]);

    int bb = (tid & 127) >> 3, jl = tid & 7, j = j0 + jl;
    float c0r = 0.f, c1r = 0.f;
    float bs0[4] = {0,0,0,0}, bs1[4] = {0,0,0,0};
    if (tid < 128) {
        float h0v = hfin[bb * 256 + j], h1v = hfin[4096 + bb * 256 + j];
        c0r = h0v; c1r = h1v;                      // source bug: c := h
        short sh, sl;
        int idx = (bb * 256 + j) >> 1;
        split2s(tef[j], &sh, &sl);
        {
            int mh = (unsigned short)sh, ml = (unsigned short)sl;
            int nh = __shfl_down(mh, 1), nl = __shfl_down(ml, 1);
            if (!(jl & 1)) { st_a((int*)teh + idx, mh | (nh << 16));
                             st_a((int*)tel + idx, ml | (nl << 16)); }
        }
        split2s(h0v, &sh, &sl);
        {
            int mh = (unsigned short)sh, ml = (unsigned short)sl;
            int nh = __shfl_down(mh, 1), nl = __shfl_down(ml, 1);
            if (!(jl & 1)) { st_a((int*)h0ih + idx, mh | (nh << 16));
                             st_a((int*)h0il + idx, ml | (nl << 16)); }
        }
        split2s(h1v, &sh, &sl);
        {
            int mh = (unsigned short)sh, ml = (unsigned short)sl;
            int nh = __shfl_down(mh, 1), nl = __shfl_down(ml, 1);
            if (!(jl & 1)) { st_a((int*)h1ih + idx, mh | (nh << 16));
                             st_a((int*)h1il + idx, ml | (nl << 16)); }
        }
#pragma unroll
        for (int q = 0; q < 4; ++q) {
            bs0[q] = dbih[q*256+j] + dbhh[q*256+j];
            bs1[q] = dbih[GG + q*256+j] + dbhh[GG + q*256+j];
        }
    }
    int gen = 0;
    gbar(flags, ++gen);

    int lane = tid & 63, w = tid >> 6, cc = lane & 15, g4 = lane >> 4, koff = g4 * 8;
    int tw = w & 1, kb = (w >> 1) * 128;       // tile / K-half per wave
    int aoff0 = cc * 256 + kb + koff;
    int woff = (tw * 16 + cc) * KP + kb + koff;

    for (int t = 0; t < TT - 1; ++t) {
        int pb = (t - 1) & 1;
        // ---- phase A: layer 0 ----
        {
            const short* xh = (t ? h1bh + pb * 4096 : teh) + aoff0;
            const short* xl = (t ? h1bl + pb * 4096 : tel) + aoff0;
            const short* hh = (t ? h0bh + pb * 4096 : h0ih) + aoff0;
            const short* hl = (t ? h0bl + pb * 4096 : h0il) + aoff0;
            f32x4 acc1 = {0.f, 0.f, 0.f, 0.f}, acc2 = {0.f, 0.f, 0.f, 0.f};
#pragma unroll
            for (int k = 0; k < 128; k += 32) {
                short8 a = ld_frag(xh + k), b = ld_frag(xl + k);
                acc1 = MFMA(a, *(const short8*)(Wl[0] + woff + k), acc1);
                acc2 = MFMA(a, *(const short8*)(Wl[1] + woff + k), acc2);
                acc2 = MFMA(b, *(const short8*)(Wl[0] + woff + k), acc2);
                short8 c = ld_frag(hh + k), d = ld_frag(hl + k);
                acc1 = MFMA(c, *(const short8*)(Wl[2] + woff + k), acc1);
                acc2 = MFMA(c, *(const short8*)(Wl[3] + woff + k), acc2);
                acc2 = MFMA(d, *(const short8*)(Wl[2] + woff + k), acc2);
            }
            f32x4 accs = acc1 + acc2;
#pragma unroll
            for (int r = 0; r < 4; ++r) gacc[w][g4 * 4 + r][cc] = accs[r];
        }
        __syncthreads();
        if (tid < 128) {
            float gv[4];
#pragma unroll
            for (int q = 0; q < 4; ++q) {
                int lr = q * 8 + jl;
                gv[q] = gacc[lr >> 4][bb][lr & 15] + gacc[2 + (lr >> 4)][bb][lr & 15] + bs0[q];
            }
            float c = sigm(gv[1]) * c0r + sigm(gv[0]) * tanh_f(gv[2]);
            c0r = c;
            float h = sigm(gv[3]) * tanh_f(c);
            short sh, sl; split2s(h, &sh, &sl);
            int mh = (unsigned short)sh, ml = (unsigned short)sl;
            int nh = __shfl_down(mh, 1), nl = __shfl_down(ml, 1);
            if (!(jl & 1)) {
                int idx = (bb * 256 + j) >> 1;
                st_a((int*)h0bh + (t & 1) * 2048 + idx, mh | (nh << 16));
                st_a((int*)h0bl + (t & 1) * 2048 + idx, ml | (nl << 16));
            }
        }
        gbar(flags, ++gen);
        // ---- phase B: layer 1 ----
        {
            const short* xh = h0bh + (t & 1) * 4096 + aoff0;
            const short* xl = h0bl + (t & 1) * 4096 + aoff0;
            const short* hh = (t ? h1bh + pb * 4096 : h1ih) + aoff0;
            const short* hl = (t ? h1bl + pb * 4096 : h1il) + aoff0;
            f32x4 acc1 = {0.f, 0.f, 0.f, 0.f}, acc2 = {0.f, 0.f, 0.f, 0.f};
#pragma unroll
            for (int k = 0; k < 128; k += 32) {
                short8 a = ld_frag(xh + k), b = ld_frag(xl + k);
                acc1 = MFMA(a, *(const short8*)(Wl[4] + woff + k), acc1);
                acc2 = MFMA(a, *(const short8*)(Wl[5] + woff + k), acc2);
                acc2 = MFMA(b, *(const short8*)(Wl[4] + woff + k), acc2);
                short8 c = ld_frag(hh + k), d = ld_frag(hl + k);
                acc1 = MFMA(c, *(const short8*)(Wl[6] + woff + k), acc1);
                acc2 = MFMA(c, *(const short8*)(Wl[7] + woff + k), acc2);
                acc2 = MFMA(d, *(const short8*)(Wl[6] + woff + k), acc2);
            }
            f32x4 accs = acc1 + acc2;
#pragma unroll
            for (int r = 0; r < 4; ++r) gacc[w][g4 * 4 + r][cc] = accs[r];
        }
        __syncthreads();
        if (tid < 128) {
            float gv[4];
#pragma unroll
            for (int q = 0; q < 4; ++q) {
                int lr = q * 8 + jl;
                gv[q] = gacc[lr >> 4][bb][lr & 15] + gacc[2 + (lr >> 4)][bb][lr & 15] + bs1[q];
            }
            float c = sigm(gv[1]) * c1r + sigm(gv[0]) * tanh_f(gv[2]);
            c1r = c;
            float h = sigm(gv[3]) * tanh_f(c);
            short sh, sl; split2s(h, &sh, &sl);
            int mh = (unsigned short)sh, ml = (unsigned short)sl;
            int nh = __shfl_down(mh, 1), nl = __shfl_down(ml, 1);
            if (!(jl & 1)) {
                int idx = (bb * 256 + j) >> 1;
                st_a((int*)h1bh + (t & 1) * 2048 + idx, mh | (nh << 16));
                st_a((int*)h1bl + (t & 1) * 2048 + idx, ml | (nl << 16));
            }
            preds[((long)(t + 1) * BB + bb) * HH + j] = h;
        }
        gbar(flags, ++gen);
    }
}

// ---------------- host launch ----------------
extern "C" void kernel_launch(void* const* d_in, const int* in_sizes, int n_in,
                              void* d_out, int out_size, void* d_ws, size_t ws_size,
                              hipStream_t stream) {
    const int*   src   = (const int*)  d_in[0];
    const float* te    = (const float*)d_in[2];
    const float* h0    = (const float*)d_in[3];
    const float* c0    = (const float*)d_in[4];
    const float* table = (const float*)d_in[5];
    const float* eWih  = (const float*)d_in[6];
    const float* eWhh  = (const float*)d_in[7];
    const float* ebih  = (const float*)d_in[8];
    const float* ebhh  = (const float*)d_in[9];
    const float* dWih  = (const float*)d_in[10];
    const float* dWhh  = (const float*)d_in[11];
    const float* dbih  = (const float*)d_in[12];
    const float* dbhh  = (const float*)d_in[13];
    float* preds = (float*)d_out;

    const int WN = GG * EE;                  // 262144 elems per layer-matrix
    const size_t MB = 1u << 20;
    char* ws = (char*)d_ws;
    short* eWih_hi = (short*)(ws + 0 * MB);
    short* eWih_lo = (short*)(ws + 1 * MB);
    short* eWhh_hi = (short*)(ws + 2 * MB);
    short* eWhh_lo = (short*)(ws + 3 * MB);
    short* dWih_hi = (short*)(ws + 4 * MB);
    short* dWih_lo = (short*)(ws + 5 * MB);
    short* dWhh_hi = (short*)(ws + 6 * MB);
    short* dWhh_lo = (short*)(ws + 7 * MB);
    short* Xa_hi   = (short*)(ws + 8 * MB);      // [4096,256]
    short* Xa_lo   = (short*)(ws + 10 * MB);
    float* hfin    = (float*)(ws + 12 * MB);     // [2,16,256]
    int*   flags   = (int*)  (ws + 12 * MB + (64 << 10));   // enc: +0, dec: +32
    short* eb      = (short*)(ws + 12 * MB + (128 << 10));  // enc h bufs 4x8192
    short* db      = (short*)(ws + 12 * MB + (256 << 10));  // dec bufs
    float* gates0  = (float*)(ws + 16 * MB);     // [4096,1024] f32

    k_binit<<<1, 64, 0, stream>>>(flags);

    k_cvt2<<<2048, 256, 0, stream>>>(eWih, (__hip_bfloat16*)eWih_hi, (__hip_bfloat16*)eWih_lo, 2 * WN);
    k_cvt2<<<2048, 256, 0, stream>>>(eWhh, (__hip_bfloat16*)eWhh_hi, (__hip_bfloat16*)eWhh_lo, 2 * WN);
    k_cvt2<<<2048, 256, 0, stream>>>(dWih, (__hip_bfloat16*)dWih_hi, (__hip_bfloat16*)dWih_lo, 2 * WN);
    k_cvt2<<<2048, 256, 0, stream>>>(dWhh, (__hip_bfloat16*)dWhh_hi, (__hip_bfloat16*)dWhh_lo, 2 * WN);

    // encoder L0 input-side GEMM (parallel), then cooperative 2-layer wavefront scan
    k_embed<<<4096, 256, 0, stream>>>(src, table, (__hip_bfloat16*)Xa_hi, (__hip_bfloat16*)Xa_lo);
    k_gemm_in<<<4096, 256, 0, stream>>>((__hip_bfloat16*)Xa_hi, (__hip_bfloat16*)Xa_lo,
                                        (__hip_bfloat16*)eWih_hi, (__hip_bfloat16*)eWih_lo,
                                        ebih, ebhh, gates0);
    k_enc_coop<<<NWG, 256, 0, stream>>>(gates0, eWhh_hi, eWhh_lo,
                                        eWih_hi + WN, eWih_lo + WN, eWhh_hi + WN, eWhh_lo + WN,
                                        ebih + GG, ebhh + GG, h0, c0,
                                        eb, eb + 8192, eb + 16384, eb + 24576,
                                        hfin, flags);

    // decoder cooperative scan
    k_dec_coop<<<NWG, 256, 0, stream>>>(dWih_hi, dWih_lo, dWhh_hi, dWhh_lo,
                                        dbih, dbhh, te, hfin,
                                        db, db + 8192, db + 16384, db + 24576,
                                        db + 32768, db + 36864, db + 40960, db + 45056,
                                        db + 49152, db + 53248,
                                        preds, flags + 32);

    // predictions[0] = 0
    k_zero<<<16, 256, 0, stream>>>(preds);
}

// Round 5
// 3026.005 us; speedup vs baseline: 1.7604x; 1.7604x over previous
//
#include <hip/hip_runtime.h>
#include <hip/hip_bf16.h>

typedef __attribute__((ext_vector_type(8))) short short8;
typedef __attribute__((ext_vector_type(4))) float f32x4;
typedef unsigned long long u64;

#define SEQ   256   // source length S
#define BB    16    // batch
#define EE    256   // embed dim
#define HH    256   // hidden
#define GG    1024  // 4*H
#define TT    128   // target_size
#define NWG   32    // persistent workgroups
#define KP    264   // LDS row stride in shorts (breaks 512B-stride bank conflicts)

__device__ __forceinline__ float sigm(float x) { return 1.0f / (1.0f + __expf(-x)); }
__device__ __forceinline__ float tanh_f(float x) {
    float e = __expf(2.0f * x);
    return 1.0f - 2.0f / (e + 1.0f);
}
__device__ __forceinline__ void split2s(float v, short* hi, short* lo) {
    __hip_bfloat16 h = __float2bfloat16(v);
    __hip_bfloat16 l = __float2bfloat16(v - __bfloat162float(h));
    *hi = *(short*)&h; *lo = *(short*)&l;
}
__device__ __forceinline__ f32x4 MFMA(short8 a, short8 b, f32x4 c) {
    return __builtin_amdgcn_mfma_f32_16x16x32_bf16(a, b, c, 0, 0, 0);
}

// ---- LLC-coherent accesses (sc0/sc1, bypass per-XCD L2; no cache-maintenance) ----
__device__ __forceinline__ int ld_a(const int* p) {
    return __hip_atomic_load(p, __ATOMIC_RELAXED, __HIP_MEMORY_SCOPE_AGENT);
}
__device__ __forceinline__ void st_a(int* p, int v) {
    __hip_atomic_store(p, v, __ATOMIC_RELAXED, __HIP_MEMORY_SCOPE_AGENT);
}
__device__ __forceinline__ u64 ld8(const u64* p) {
    return __hip_atomic_load(p, __ATOMIC_RELAXED, __HIP_MEMORY_SCOPE_AGENT);
}
union S8U { u64 q[2]; short8 s; };
__device__ __forceinline__ short8 mk8(u64 a, u64 b) { S8U u; u.q[0] = a; u.q[1] = b; return u.s; }

// ---- grid barrier: flag-array, relaxed agent atomics, explicit vmcnt drain ----
__device__ __forceinline__ void gbar(int* flags, int target) {
    __syncthreads();                         // all waves drain vmcnt before s_barrier
    asm volatile("s_waitcnt vmcnt(0)" ::: "memory");
    if (threadIdx.x == 0) st_a(&flags[blockIdx.x], target);
    if (threadIdx.x < 64) {
        int i = threadIdx.x & 31;
        while (ld_a(&flags[i]) < target) __builtin_amdgcn_s_sleep(1);
    }
    asm volatile("" ::: "memory");
    __syncthreads();
}

// ---------------- utility kernels ----------------
__global__ void k_binit(int* p) { if (threadIdx.x < 64) p[threadIdx.x] = 0; }

__global__ void k_cvt2(const float* __restrict__ s, __hip_bfloat16* __restrict__ hi,
                       __hip_bfloat16* __restrict__ lo, int n) {
    int i = blockIdx.x * 256 + threadIdx.x;
    if (i < n) {
        short a, b; split2s(s[i], &a, &b);
        hi[i] = *(__hip_bfloat16*)&a; lo[i] = *(__hip_bfloat16*)&b;
    }
}

__global__ void k_zero(float* __restrict__ p) {
    p[blockIdx.x * 256 + threadIdx.x] = 0.0f;
}

__global__ void k_embed(const int* __restrict__ src, const float* __restrict__ tab,
                        __hip_bfloat16* __restrict__ xhi, __hip_bfloat16* __restrict__ xlo) {
    int r = blockIdx.x;          // r = t*B + b
    int j = threadIdx.x;
    long idx = src[r];
    short a, b; split2s(tab[idx * EE + j], &a, &b);
    xhi[(long)r * EE + j] = *(__hip_bfloat16*)&a;
    xlo[(long)r * EE + j] = *(__hip_bfloat16*)&b;
}

// ------------- input-side GEMM: gates0 = X @ Wih0^T + bih0 + bhh0 (f32-accurate) -------------
__global__ void __launch_bounds__(256) k_gemm_in(
        const __hip_bfloat16* __restrict__ Xhi, const __hip_bfloat16* __restrict__ Xlo,
        const __hip_bfloat16* __restrict__ Whi, const __hip_bfloat16* __restrict__ Wlo,
        const float* __restrict__ bih, const float* __restrict__ bhh,
        float* __restrict__ gates) {
    int lane = threadIdx.x & 63, w = threadIdx.x >> 6;
    int m0 = (blockIdx.x >> 4) * 16;
    int n0 = ((blockIdx.x & 15) * 4 + w) * 16;
    int cc = lane & 15, g = lane >> 4;
    int koff = g * 8;
    const short* xh = (const short*)Xhi + (long)(m0 + cc) * EE + koff;
    const short* xl = (const short*)Xlo + (long)(m0 + cc) * EE + koff;
    const short* wh = (const short*)Whi + (long)(n0 + cc) * EE + koff;
    const short* wl = (const short*)Wlo + (long)(n0 + cc) * EE + koff;
    f32x4 acc1 = {0.f, 0.f, 0.f, 0.f}, acc2 = {0.f, 0.f, 0.f, 0.f};
#pragma unroll
    for (int k = 0; k < EE; k += 32) {
        short8 ah = *(const short8*)(xh + k), al = *(const short8*)(xl + k);
        short8 bh = *(const short8*)(wh + k), bl = *(const short8*)(wl + k);
        acc1 = MFMA(ah, bh, acc1);
        acc2 = MFMA(ah, bl, acc2);
        acc2 = MFMA(al, bh, acc2);
    }
    f32x4 acc = acc1 + acc2;
    int ncol = n0 + cc;
    float bias = bih[ncol] + bhh[ncol];
    int mrow = m0 + g * 4;
#pragma unroll
    for (int r = 0; r < 4; ++r)
        gates[(long)(mrow + r) * GG + ncol] = acc[r] + bias;
}

// ---- gather one 32-row weight slice (rows q*256+j0+jl -> lr=q*8+jl) into LDS ----
__device__ __forceinline__ void load_wslice(const short* __restrict__ Wg, int j0,
                                            short* __restrict__ Wl) {
    int tid = threadIdx.x;
    int lr = tid >> 3;                 // 0..31
    int q = lr >> 3, jl = lr & 7;
    const short* src = Wg + (long)(q * 256 + j0 + jl) * 256;
    short* dst = Wl + lr * KP;
#pragma unroll
    for (int s = 0; s < 4; ++s) {
        int c = (tid & 7) * 8 + s * 64;
        *(short8*)(dst + c) = *(const short8*)(src + c);
    }
}

// ---------------- encoder: both layers, wavefront (L1 one step behind L0) ----------------
// 32 blocks x 256 thr; K-split balance: wave w does L0 tile (w&1) K-half (w>>1)
// plus L1 tile (w&1) same K-half (x-fragment registers shared with L0).
__global__ void __launch_bounds__(256, 1) k_enc_coop(
        const float* __restrict__ gates0,                  // [S*B][G] L0 x-gates + bias
        const short* __restrict__ Whh0h, const short* __restrict__ Whh0l,
        const short* __restrict__ Wih1h, const short* __restrict__ Wih1l,
        const short* __restrict__ Whh1h, const short* __restrict__ Whh1l,
        const float* __restrict__ bih1, const float* __restrict__ bhh1,
        const float* __restrict__ h0p, const float* __restrict__ c0p,  // [2][16][256]
        short* __restrict__ h0bh, short* __restrict__ h0bl,  // [2][4096] double buf
        short* __restrict__ h1bh, short* __restrict__ h1bl,
        float* __restrict__ hfin, int* __restrict__ flags) {
    __shared__ short Wl[6][32 * KP];
    __shared__ float gacc[8][16][17];

    int tid = threadIdx.x;
    int j0 = blockIdx.x * 8;
    load_wslice(Whh0h, j0, Wl[0]); load_wslice(Whh0l, j0, Wl[1]);
    load_wslice(Wih1h, j0, Wl[2]); load_wslice(Wih1l, j0, Wl[3]);
    load_wslice(Whh1h, j0, Wl[4]); load_wslice(Whh1l, j0, Wl[5]);

    int bb = (tid & 127) >> 3, jl = tid & 7, j = j0 + jl, lay = tid >> 7;
    float creg = c0p[lay * 4096 + bb * 256 + j];
    float bs[4] = {0.f, 0.f, 0.f, 0.f};
    if (lay) {
#pragma unroll
        for (int q = 0; q < 4; ++q) bs[q] = bih1[q * 256 + j] + bhh1[q * 256 + j];
    }
    {   // init: L0 state -> buf1 (read at i=0), L1 state -> buf0 (read at i=1)
        float hv = h0p[lay * 4096 + bb * 256 + j];
        short sh, sl; split2s(hv, &sh, &sl);
        int mh = (unsigned short)sh, ml = (unsigned short)sl;
        int nh = __shfl_down(mh, 1), nl = __shfl_down(ml, 1);
        short* dh = lay ? h1bh : (h0bh + 4096);
        short* dl = lay ? h1bl : (h0bl + 4096);
        if (!(jl & 1)) {
            st_a((int*)dh + ((bb * 256 + j) >> 1), mh | (nh << 16));
            st_a((int*)dl + ((bb * 256 + j) >> 1), ml | (nl << 16));
        }
    }
    int gen = 0;
    gbar(flags, ++gen);

    int lane = tid & 63, w = tid >> 6, cc = lane & 15, g4 = lane >> 4, koff = g4 * 8;
    int tw = w & 1, kb = (w >> 1) * 128;
    int off = ((cc << 8) + kb + koff) >> 2;        // u64 index into a 4096-short plane
    int wr = (tw * 16 + cc) * KP + kb + koff;

    for (int i = 0; i <= SEQ; ++i) {
        int rb = (i + 1) & 1, wb = i & 1;
        bool actL0 = (i < SEQ), actL1 = (i >= 1);

        float gpre[4] = {0.f, 0.f, 0.f, 0.f};
        if (!lay && actL0) {     // prefetch L0 x-side gates (plain cached loads)
#pragma unroll
            for (int q = 0; q < 4; ++q)
                gpre[q] = gates0[(long)(i * BB + bb) * GG + q * 256 + j];
        }

        // -------- hoisted LLC loads: issue everything, then compute --------
        u64 a0h[8], a0l[8], a1h[8], a1l[8];
        {
            const u64* p0h = (const u64*)(h0bh + rb * 4096) + off;
            const u64* p0l = (const u64*)(h0bl + rb * 4096) + off;
#pragma unroll
            for (int ki = 0; ki < 4; ++ki) {
                a0h[2*ki] = ld8(p0h + ki*8); a0h[2*ki+1] = ld8(p0h + ki*8 + 1);
                a0l[2*ki] = ld8(p0l + ki*8); a0l[2*ki+1] = ld8(p0l + ki*8 + 1);
            }
            if (actL1) {
                const u64* p1h = (const u64*)(h1bh + rb * 4096) + off;
                const u64* p1l = (const u64*)(h1bl + rb * 4096) + off;
#pragma unroll
                for (int ki = 0; ki < 4; ++ki) {
                    a1h[2*ki] = ld8(p1h + ki*8); a1h[2*ki+1] = ld8(p1h + ki*8 + 1);
                    a1l[2*ki] = ld8(p1l + ki*8); a1l[2*ki+1] = ld8(p1l + ki*8 + 1);
                }
            }
        }

        f32x4 z = {0.f, 0.f, 0.f, 0.f};
        f32x4 acc01 = z, acc02 = z, acc11 = z, acc12 = z;
        if (actL0) {
#pragma unroll
            for (int ki = 0; ki < 4; ++ki) {
                short8 ah = mk8(a0h[2*ki], a0h[2*ki+1]);
                short8 al = mk8(a0l[2*ki], a0l[2*ki+1]);
                short8 wh  = *(const short8*)(Wl[0] + wr + ki*32);
                short8 wl2 = *(const short8*)(Wl[1] + wr + ki*32);
                acc01 = MFMA(ah, wh, acc01);
                acc02 = MFMA(ah, wl2, acc02);
                acc02 = MFMA(al, wh, acc02);
            }
        }
        if (actL1) {
#pragma unroll
            for (int ki = 0; ki < 4; ++ki) {
                short8 xh = mk8(a0h[2*ki], a0h[2*ki+1]);   // x = h0(prev): reuse regs
                short8 xl = mk8(a0l[2*ki], a0l[2*ki+1]);
                short8 hh = mk8(a1h[2*ki], a1h[2*ki+1]);
                short8 hl = mk8(a1l[2*ki], a1l[2*ki+1]);
                acc11 = MFMA(xh, *(const short8*)(Wl[2] + wr + ki*32), acc11);
                acc12 = MFMA(xh, *(const short8*)(Wl[3] + wr + ki*32), acc12);
                acc12 = MFMA(xl, *(const short8*)(Wl[2] + wr + ki*32), acc12);
                acc11 = MFMA(hh, *(const short8*)(Wl[4] + wr + ki*32), acc11);
                acc12 = MFMA(hh, *(const short8*)(Wl[5] + wr + ki*32), acc12);
                acc12 = MFMA(hl, *(const short8*)(Wl[4] + wr + ki*32), acc12);
            }
        }
        f32x4 s0 = acc01 + acc02, s1 = acc11 + acc12;
#pragma unroll
        for (int r = 0; r < 4; ++r) {
            gacc[w][g4 * 4 + r][cc] = s0[r];
            gacc[4 + w][g4 * 4 + r][cc] = s1[r];
        }
        __syncthreads();

        bool act = lay ? actL1 : actL0;
        if (act) {
            int t = lay ? (i - 1) : i;
            float gv[4];
#pragma unroll
            for (int q = 0; q < 4; ++q) {
                int lr = q * 8 + jl, tl = lr >> 4, c = lr & 15;
                gv[q] = lay ? (gacc[4 + tl][bb][c] + gacc[6 + tl][bb][c] + bs[q])
                            : (gacc[tl][bb][c] + gacc[2 + tl][bb][c] + gpre[q]);
            }
            float c = sigm(gv[1]) * creg + sigm(gv[0]) * tanh_f(gv[2]);
            creg = c;
            float h = sigm(gv[3]) * tanh_f(c);
            short sh, sl; split2s(h, &sh, &sl);
            int mh = (unsigned short)sh, ml = (unsigned short)sl;
            int nh = __shfl_down(mh, 1), nl = __shfl_down(ml, 1);
            short* dh = (lay ? h1bh : h0bh) + wb * 4096;
            short* dl = (lay ? h1bl : h0bl) + wb * 4096;
            if (!(jl & 1)) {
                st_a((int*)dh + ((bb * 256 + j) >> 1), mh | (nh << 16));
                st_a((int*)dl + ((bb * 256 + j) >> 1), ml | (nl << 16));
            }
            if (t == SEQ - 1) hfin[lay * 4096 + bb * 256 + j] = h;
        }
        gbar(flags, ++gen);
    }
}

// ---------------- decoder: 2 phases/step (L0 then L1), weights LDS-resident ----------------
__global__ void __launch_bounds__(256, 1) k_dec_coop(
        const short* __restrict__ Wihh, const short* __restrict__ Wihl,   // [2][1024][256]
        const short* __restrict__ Whhh, const short* __restrict__ Whhl,
        const float* __restrict__ dbih, const float* __restrict__ dbhh,   // [2][1024]
        const float* __restrict__ tef, const float* __restrict__ hfin,
        short* __restrict__ h0bh, short* __restrict__ h0bl,   // [2][4096]
        short* __restrict__ h1bh, short* __restrict__ h1bl,
        short* __restrict__ teh, short* __restrict__ tel,     // [4096] init bufs
        short* __restrict__ h0ih, short* __restrict__ h0il,
        short* __restrict__ h1ih, short* __restrict__ h1il,
        float* __restrict__ preds, int* __restrict__ flags) {
    __shared__ short Wl[8][32 * KP];
    __shared__ float gacc[4][16][17];
    const int WN = GG * EE;

    int tid = threadIdx.x;
    int j0 = blockIdx.x * 8;
    load_wslice(Wihh, j0, Wl[0]);      load_wslice(Wihl, j0, Wl[1]);
    load_wslice(Whhh, j0, Wl[2]);      load_wslice(Whhl, j0, Wl[3]);
    load_wslice(Wihh + WN, j0, Wl[4]); load_wslice(Wihl + WN, j0, Wl[5]);
    load_wslice(Whhh + WN, j0, Wl[6]); load_wslice(Whhl + WN, j0, Wl[7]);

    int bb = (tid & 127) >> 3, jl = tid & 7, j = j0 + jl;
    float c0r = 0.f, c1r = 0.f;
    float bs0[4] = {0,0,0,0}, bs1[4] = {0,0,0,0};
    if (tid < 128) {
        float h0v = hfin[bb * 256 + j], h1v = hfin[4096 + bb * 256 + j];
        c0r = h0v; c1r = h1v;                      // source bug: c := h
        short sh, sl;
        int idx = (bb * 256 + j) >> 1;
        split2s(tef[j], &sh, &sl);
        {
            int mh = (unsigned short)sh, ml = (unsigned short)sl;
            int nh = __shfl_down(mh, 1), nl = __shfl_down(ml, 1);
            if (!(jl & 1)) { st_a((int*)teh + idx, mh | (nh << 16));
                             st_a((int*)tel + idx, ml | (nl << 16)); }
        }
        split2s(h0v, &sh, &sl);
        {
            int mh = (unsigned short)sh, ml = (unsigned short)sl;
            int nh = __shfl_down(mh, 1), nl = __shfl_down(ml, 1);
            if (!(jl & 1)) { st_a((int*)h0ih + idx, mh | (nh << 16));
                             st_a((int*)h0il + idx, ml | (nl << 16)); }
        }
        split2s(h1v, &sh, &sl);
        {
            int mh = (unsigned short)sh, ml = (unsigned short)sl;
            int nh = __shfl_down(mh, 1), nl = __shfl_down(ml, 1);
            if (!(jl & 1)) { st_a((int*)h1ih + idx, mh | (nh << 16));
                             st_a((int*)h1il + idx, ml | (nl << 16)); }
        }
#pragma unroll
        for (int q = 0; q < 4; ++q) {
            bs0[q] = dbih[q*256+j] + dbhh[q*256+j];
            bs1[q] = dbih[GG + q*256+j] + dbhh[GG + q*256+j];
        }
    }
    int gen = 0;
    gbar(flags, ++gen);

    int lane = tid & 63, w = tid >> 6, cc = lane & 15, g4 = lane >> 4, koff = g4 * 8;
    int tw = w & 1, kb = (w >> 1) * 128;       // tile / K-half per wave
    int off = ((cc << 8) + kb + koff) >> 2;    // u64 index
    int wr = (tw * 16 + cc) * KP + kb + koff;

    for (int t = 0; t < TT - 1; ++t) {
        int pb = (t - 1) & 1;
        // ---- phase A: layer 0 : x = h1(t-1), h = h0(t-1) ----
        {
            const u64* pxh = (const u64*)((t ? h1bh + pb * 4096 : teh)) + off;
            const u64* pxl = (const u64*)((t ? h1bl + pb * 4096 : tel)) + off;
            const u64* phh = (const u64*)((t ? h0bh + pb * 4096 : h0ih)) + off;
            const u64* phl = (const u64*)((t ? h0bl + pb * 4096 : h0il)) + off;
            u64 xh[8], xl[8], hh[8], hl[8];
#pragma unroll
            for (int ki = 0; ki < 4; ++ki) {
                xh[2*ki] = ld8(pxh + ki*8); xh[2*ki+1] = ld8(pxh + ki*8 + 1);
                xl[2*ki] = ld8(pxl + ki*8); xl[2*ki+1] = ld8(pxl + ki*8 + 1);
                hh[2*ki] = ld8(phh + ki*8); hh[2*ki+1] = ld8(phh + ki*8 + 1);
                hl[2*ki] = ld8(phl + ki*8); hl[2*ki+1] = ld8(phl + ki*8 + 1);
            }
            f32x4 acc1 = {0.f,0.f,0.f,0.f}, acc2 = {0.f,0.f,0.f,0.f};
#pragma unroll
            for (int ki = 0; ki < 4; ++ki) {
                short8 a = mk8(xh[2*ki], xh[2*ki+1]), b = mk8(xl[2*ki], xl[2*ki+1]);
                acc1 = MFMA(a, *(const short8*)(Wl[0] + wr + ki*32), acc1);
                acc2 = MFMA(a, *(const short8*)(Wl[1] + wr + ki*32), acc2);
                acc2 = MFMA(b, *(const short8*)(Wl[0] + wr + ki*32), acc2);
                short8 c = mk8(hh[2*ki], hh[2*ki+1]), d = mk8(hl[2*ki], hl[2*ki+1]);
                acc1 = MFMA(c, *(const short8*)(Wl[2] + wr + ki*32), acc1);
                acc2 = MFMA(c, *(const short8*)(Wl[3] + wr + ki*32), acc2);
                acc2 = MFMA(d, *(const short8*)(Wl[2] + wr + ki*32), acc2);
            }
            f32x4 accs = acc1 + acc2;
#pragma unroll
            for (int r = 0; r < 4; ++r) gacc[w][g4 * 4 + r][cc] = accs[r];
        }
        __syncthreads();
        if (tid < 128) {
            float gv[4];
#pragma unroll
            for (int q = 0; q < 4; ++q) {
                int lr = q * 8 + jl;
                gv[q] = gacc[lr >> 4][bb][lr & 15] + gacc[2 + (lr >> 4)][bb][lr & 15] + bs0[q];
            }
            float c = sigm(gv[1]) * c0r + sigm(gv[0]) * tanh_f(gv[2]);
            c0r = c;
            float h = sigm(gv[3]) * tanh_f(c);
            short sh, sl; split2s(h, &sh, &sl);
            int mh = (unsigned short)sh, ml = (unsigned short)sl;
            int nh = __shfl_down(mh, 1), nl = __shfl_down(ml, 1);
            if (!(jl & 1)) {
                int idx = (bb * 256 + j) >> 1;
                st_a((int*)h0bh + (t & 1) * 2048 + idx, mh | (nh << 16));
                st_a((int*)h0bl + (t & 1) * 2048 + idx, ml | (nl << 16));
            }
        }
        gbar(flags, ++gen);
        // ---- phase B: layer 1 : x = h0(t), h = h1(t-1) ----
        {
            const u64* pxh = (const u64*)(h0bh + (t & 1) * 4096) + off;
            const u64* pxl = (const u64*)(h0bl + (t & 1) * 4096) + off;
            const u64* phh = (const u64*)((t ? h1bh + pb * 4096 : h1ih)) + off;
            const u64* phl = (const u64*)((t ? h1bl + pb * 4096 : h1il)) + off;
            u64 xh[8], xl[8], hh[8], hl[8];
#pragma unroll
            for (int ki = 0; ki < 4; ++ki) {
                xh[2*ki] = ld8(pxh + ki*8); xh[2*ki+1] = ld8(pxh + ki*8 + 1);
                xl[2*ki] = ld8(pxl + ki*8); xl[2*ki+1] = ld8(pxl + ki*8 + 1);
                hh[2*ki] = ld8(phh + ki*8); hh[2*ki+1] = ld8(phh + ki*8 + 1);
                hl[2*ki] = ld8(phl + ki*8); hl[2*ki+1] = ld8(phl + ki*8 + 1);
            }
            f32x4 acc1 = {0.f,0.f,0.f,0.f}, acc2 = {0.f,0.f,0.f,0.f};
#pragma unroll
            for (int ki = 0; ki < 4; ++ki) {
                short8 a = mk8(xh[2*ki], xh[2*ki+1]), b = mk8(xl[2*ki], xl[2*ki+1]);
                acc1 = MFMA(a, *(const short8*)(Wl[4] + wr + ki*32), acc1);
                acc2 = MFMA(a, *(const short8*)(Wl[5] + wr + ki*32), acc2);
                acc2 = MFMA(b, *(const short8*)(Wl[4] + wr + ki*32), acc2);
                short8 c = mk8(hh[2*ki], hh[2*ki+1]), d = mk8(hl[2*ki], hl[2*ki+1]);
                acc1 = MFMA(c, *(const short8*)(Wl[6] + wr + ki*32), acc1);
                acc2 = MFMA(c, *(const short8*)(Wl[7] + wr + ki*32), acc2);
                acc2 = MFMA(d, *(const short8*)(Wl[6] + wr + ki*32), acc2);
            }
            f32x4 accs = acc1 + acc2;
#pragma unroll
            for (int r = 0; r < 4; ++r) gacc[w][g4 * 4 + r][cc] = accs[r];
        }
        __syncthreads();
        if (tid < 128) {
            float gv[4];
#pragma unroll
            for (int q = 0; q < 4; ++q) {
                int lr = q * 8 + jl;
                gv[q] = gacc[lr >> 4][bb][lr & 15] + gacc[2 + (lr >> 4)][bb][lr & 15] + bs1[q];
            }
            float c = sigm(gv[1]) * c1r + sigm(gv[0]) * tanh_f(gv[2]);
            c1r = c;
            float h = sigm(gv[3]) * tanh_f(c);
            short sh, sl; split2s(h, &sh, &sl);
            int mh = (unsigned short)sh, ml = (unsigned short)sl;
            int nh = __shfl_down(mh, 1), nl = __shfl_down(ml, 1);
            if (!(jl & 1)) {
                int idx = (bb * 256 + j) >> 1;
                st_a((int*)h1bh + (t & 1) * 2048 + idx, mh | (nh << 16));
                st_a((int*)h1bl + (t & 1) * 2048 + idx, ml | (nl << 16));
            }
            preds[((long)(t + 1) * BB + bb) * HH + j] = h;
        }
        gbar(flags, ++gen);
    }
}

// ---------------- host launch ----------------
extern "C" void kernel_launch(void* const* d_in, const int* in_sizes, int n_in,
                              void* d_out, int out_size, void* d_ws, size_t ws_size,
                              hipStream_t stream) {
    const int*   src   = (const int*)  d_in[0];
    const float* te    = (const float*)d_in[2];
    const float* h0    = (const float*)d_in[3];
    const float* c0    = (const float*)d_in[4];
    const float* table = (const float*)d_in[5];
    const float* eWih  = (const float*)d_in[6];
    const float* eWhh  = (const float*)d_in[7];
    const float* ebih  = (const float*)d_in[8];
    const float* ebhh  = (const float*)d_in[9];
    const float* dWih  = (const float*)d_in[10];
    const float* dWhh  = (const float*)d_in[11];
    const float* dbih  = (const float*)d_in[12];
    const float* dbhh  = (const float*)d_in[13];
    float* preds = (float*)d_out;

    const int WN = GG * EE;                  // 262144 elems per layer-matrix
    const size_t MB = 1u << 20;
    char* ws = (char*)d_ws;
    short* eWih_hi = (short*)(ws + 0 * MB);
    short* eWih_lo = (short*)(ws + 1 * MB);
    short* eWhh_hi = (short*)(ws + 2 * MB);
    short* eWhh_lo = (short*)(ws + 3 * MB);
    short* dWih_hi = (short*)(ws + 4 * MB);
    short* dWih_lo = (short*)(ws + 5 * MB);
    short* dWhh_hi = (short*)(ws + 6 * MB);
    short* dWhh_lo = (short*)(ws + 7 * MB);
    short* Xa_hi   = (short*)(ws + 8 * MB);      // [4096,256]
    short* Xa_lo   = (short*)(ws + 10 * MB);
    float* hfin    = (float*)(ws + 12 * MB);     // [2,16,256]
    int*   flags   = (int*)  (ws + 12 * MB + (64 << 10));   // enc: +0, dec: +32
    short* eb      = (short*)(ws + 12 * MB + (128 << 10));  // enc h bufs 4x8192
    short* db      = (short*)(ws + 12 * MB + (256 << 10));  // dec bufs
    float* gates0  = (float*)(ws + 16 * MB);     // [4096,1024] f32

    k_binit<<<1, 64, 0, stream>>>(flags);

    k_cvt2<<<2048, 256, 0, stream>>>(eWih, (__hip_bfloat16*)eWih_hi, (__hip_bfloat16*)eWih_lo, 2 * WN);
    k_cvt2<<<2048, 256, 0, stream>>>(eWhh, (__hip_bfloat16*)eWhh_hi, (__hip_bfloat16*)eWhh_lo, 2 * WN);
    k_cvt2<<<2048, 256, 0, stream>>>(dWih, (__hip_bfloat16*)dWih_hi, (__hip_bfloat16*)dWih_lo, 2 * WN);
    k_cvt2<<<2048, 256, 0, stream>>>(dWhh, (__hip_bfloat16*)dWhh_hi, (__hip_bfloat16*)dWhh_lo, 2 * WN);

    // encoder L0 input-side GEMM (parallel), then cooperative 2-layer wavefront scan
    k_embed<<<4096, 256, 0, stream>>>(src, table, (__hip_bfloat16*)Xa_hi, (__hip_bfloat16*)Xa_lo);
    k_gemm_in<<<4096, 256, 0, stream>>>((__hip_bfloat16*)Xa_hi, (__hip_bfloat16*)Xa_lo,
                                        (__hip_bfloat16*)eWih_hi, (__hip_bfloat16*)eWih_lo,
                                        ebih, ebhh, gates0);
    k_enc_coop<<<NWG, 256, 0, stream>>>(gates0, eWhh_hi, eWhh_lo,
                                        eWih_hi + WN, eWih_lo + WN, eWhh_hi + WN, eWhh_lo + WN,
                                        ebih + GG, ebhh + GG, h0, c0,
                                        eb, eb + 8192, eb + 16384, eb + 24576,
                                        hfin, flags);

    // decoder cooperative scan
    k_dec_coop<<<NWG, 256, 0, stream>>>(dWih_hi, dWih_lo, dWhh_hi, dWhh_lo,
                                        dbih, dbhh, te, hfin,
                                        db, db + 8192, db + 16384, db + 24576,
                                        db + 32768, db + 36864, db + 40960, db + 45056,
                                        db + 49152, db + 53248,
                                        preds, flags + 32);

    // predictions[0] = 0
    k_zero<<<16, 256, 0, stream>>>(preds);
}

// Round 7
// 2711.266 us; speedup vs baseline: 1.9648x; 1.1161x over previous
//
#include <hip/hip_runtime.h>
#include <hip/hip_bf16.h>

typedef __attribute__((ext_vector_type(8))) short short8;
typedef __attribute__((ext_vector_type(4))) float f32x4;
typedef unsigned long long u64;

#define SEQ   256   // source length S
#define BB    16    // batch
#define EE    256   // embed dim
#define HH    256   // hidden
#define GG    1024  // 4*H
#define TT    128   // target_size
#define NWG   32    // persistent workgroups
#define KP    264   // LDS row stride in shorts (breaks 512B-stride bank conflicts)

__device__ __forceinline__ float sigm(float x) { return 1.0f / (1.0f + __expf(-x)); }
__device__ __forceinline__ float tanh_f(float x) {
    float e = __expf(2.0f * x);
    return 1.0f - 2.0f / (e + 1.0f);
}
__device__ __forceinline__ void split2s(float v, short* hi, short* lo) {
    __hip_bfloat16 h = __float2bfloat16(v);
    __hip_bfloat16 l = __float2bfloat16(v - __bfloat162float(h));
    *hi = *(short*)&h; *lo = *(short*)&l;
}
__device__ __forceinline__ f32x4 MFMA(short8 a, short8 b, f32x4 c) {
    return __builtin_amdgcn_mfma_f32_16x16x32_bf16(a, b, c, 0, 0, 0);
}

// ---- LLC-coherent access (agent scope; correct regardless of XCD placement) ----
__device__ __forceinline__ int ld_a(const int* p) {
    return __hip_atomic_load(p, __ATOMIC_RELAXED, __HIP_MEMORY_SCOPE_AGENT);
}
__device__ __forceinline__ void st_a(int* p, int v) {
    __hip_atomic_store(p, v, __ATOMIC_RELAXED, __HIP_MEMORY_SCOPE_AGENT);
}
__device__ __forceinline__ u64 ld8(const u64* p) {
    return __hip_atomic_load(p, __ATOMIC_RELAXED, __HIP_MEMORY_SCOPE_AGENT);
}
union S8U { u64 q[2]; short8 s; };
__device__ __forceinline__ short8 mk8(u64 a, u64 b) { S8U u; u.q[0] = a; u.q[1] = b; return u.s; }

// plain cached load (read-only data written before kernel launch)
__device__ __forceinline__ float lddw(const float* p) {
    float r;
    asm volatile("global_load_dword %0, %1, off" : "=v"(r) : "v"(p));
    return r;   // valid only after a vmcnt(0) drain (next gbar)
}
#define TOUCH8(x) asm volatile("" : "+v"(x))
#define TOUCHF(x) asm volatile("" : "+v"(x))

// ---- grid barrier: SPACED flag-array (64B apart), relaxed agent atomics ----
__device__ __forceinline__ void gbar(int* flags, int target) {
    __syncthreads();                         // compiler drains vmcnt before s_barrier
    asm volatile("s_waitcnt vmcnt(0)" ::: "memory");
    if (threadIdx.x == 0) st_a(&flags[(int)blockIdx.x << 4], target);
    if (threadIdx.x < 32) {
        while (ld_a(&flags[(int)threadIdx.x << 4]) < target)
            __builtin_amdgcn_s_sleep(1);
    }
    __builtin_amdgcn_sched_barrier(0);
    __syncthreads();
}

// ---------------- utility kernels ----------------
__global__ void __launch_bounds__(1024) k_binit(int* p) { p[threadIdx.x] = 0; }

__global__ void k_cvt2(const float* __restrict__ s, __hip_bfloat16* __restrict__ hi,
                       __hip_bfloat16* __restrict__ lo, int n) {
    int i = blockIdx.x * 256 + threadIdx.x;
    if (i < n) {
        short a, b; split2s(s[i], &a, &b);
        hi[i] = *(__hip_bfloat16*)&a; lo[i] = *(__hip_bfloat16*)&b;
    }
}

__global__ void k_zero(float* __restrict__ p) {
    p[blockIdx.x * 256 + threadIdx.x] = 0.0f;
}

__global__ void k_embed(const int* __restrict__ src, const float* __restrict__ tab,
                        __hip_bfloat16* __restrict__ xhi, __hip_bfloat16* __restrict__ xlo) {
    int r = blockIdx.x;          // r = t*B + b
    int j = threadIdx.x;
    long idx = src[r];
    short a, b; split2s(tab[idx * EE + j], &a, &b);
    xhi[(long)r * EE + j] = *(__hip_bfloat16*)&a;
    xlo[(long)r * EE + j] = *(__hip_bfloat16*)&b;
}

// ------------- input-side GEMM: gates0 = X @ Wih0^T + bih0 + bhh0 (f32-accurate) -------------
__global__ void __launch_bounds__(256) k_gemm_in(
        const __hip_bfloat16* __restrict__ Xhi, const __hip_bfloat16* __restrict__ Xlo,
        const __hip_bfloat16* __restrict__ Whi, const __hip_bfloat16* __restrict__ Wlo,
        const float* __restrict__ bih, const float* __restrict__ bhh,
        float* __restrict__ gates) {
    int lane = threadIdx.x & 63, w = threadIdx.x >> 6;
    int m0 = (blockIdx.x >> 4) * 16;
    int n0 = ((blockIdx.x & 15) * 4 + w) * 16;
    int cc = lane & 15, g = lane >> 4;
    int koff = g * 8;
    const short* xh = (const short*)Xhi + (long)(m0 + cc) * EE + koff;
    const short* xl = (const short*)Xlo + (long)(m0 + cc) * EE + koff;
    const short* wh = (const short*)Whi + (long)(n0 + cc) * EE + koff;
    const short* wl = (const short*)Wlo + (long)(n0 + cc) * EE + koff;
    f32x4 acc1 = {0.f, 0.f, 0.f, 0.f}, acc2 = {0.f, 0.f, 0.f, 0.f};
#pragma unroll
    for (int k = 0; k < EE; k += 32) {
        short8 ah = *(const short8*)(xh + k), al = *(const short8*)(xl + k);
        short8 bh = *(const short8*)(wh + k), bl = *(const short8*)(wl + k);
        acc1 = MFMA(ah, bh, acc1);
        acc2 = MFMA(ah, bl, acc2);
        acc2 = MFMA(al, bh, acc2);
    }
    f32x4 acc = acc1 + acc2;
    int ncol = n0 + cc;
    float bias = bih[ncol] + bhh[ncol];
    int mrow = m0 + g * 4;
#pragma unroll
    for (int r = 0; r < 4; ++r)
        gates[(long)(mrow + r) * GG + ncol] = acc[r] + bias;
}

// ---- gather one 32-row weight slice (rows q*256+j0+jl -> lr=q*8+jl) into LDS ----
__device__ __forceinline__ void load_wslice(const short* __restrict__ Wg, int j0,
                                            short* __restrict__ Wl) {
    int tid = threadIdx.x;
    int lr = tid >> 3;                 // 0..31
    int q = lr >> 3, jl = lr & 7;
    const short* src = Wg + (long)(q * 256 + j0 + jl) * 256;
    short* dst = Wl + lr * KP;
#pragma unroll
    for (int s = 0; s < 4; ++s) {
        int c = (tid & 7) * 8 + s * 64;
        *(short8*)(dst + c) = *(const short8*)(src + c);
    }
}

// ---------------- encoder: both layers, wavefront (L1 one step behind L0) ----------------
__global__ void __launch_bounds__(256, 1) k_enc_coop(
        const float* __restrict__ gates0,                  // [S*B][G] L0 x-gates + bias
        const short* __restrict__ Whh0h, const short* __restrict__ Whh0l,
        const short* __restrict__ Wih1h, const short* __restrict__ Wih1l,
        const short* __restrict__ Whh1h, const short* __restrict__ Whh1l,
        const float* __restrict__ bih1, const float* __restrict__ bhh1,
        const float* __restrict__ h0p, const float* __restrict__ c0p,  // [2][16][256]
        short* __restrict__ h0bh, short* __restrict__ h0bl,  // [2][4096] double buf
        short* __restrict__ h1bh, short* __restrict__ h1bl,
        float* __restrict__ hfin, int* __restrict__ flags) {
    __shared__ short Wl[6][32 * KP];
    __shared__ float gacc[8][16][17];

    int tid = threadIdx.x;
    int j0 = blockIdx.x * 8;
    load_wslice(Whh0h, j0, Wl[0]); load_wslice(Whh0l, j0, Wl[1]);
    load_wslice(Wih1h, j0, Wl[2]); load_wslice(Wih1l, j0, Wl[3]);
    load_wslice(Whh1h, j0, Wl[4]); load_wslice(Whh1l, j0, Wl[5]);

    int bb = (tid & 127) >> 3, jl = tid & 7, j = j0 + jl, lay = tid >> 7;
    float creg = c0p[lay * 4096 + bb * 256 + j];
    float bs[4] = {0.f, 0.f, 0.f, 0.f};
    if (lay) {
#pragma unroll
        for (int q = 0; q < 4; ++q) bs[q] = bih1[q * 256 + j] + bhh1[q * 256 + j];
    }
    float gnew[4] = {0.f, 0.f, 0.f, 0.f};
    if (!lay) {                         // gates for t=0 (pre-loop, plain loads)
#pragma unroll
        for (int q = 0; q < 4; ++q) gnew[q] = gates0[(long)bb * GG + q * 256 + j];
    }
    {   // init: L0 state -> buf1 (read at i=0), L1 state -> buf0 (read at i=1)
        float hv = h0p[lay * 4096 + bb * 256 + j];
        short sh, sl; split2s(hv, &sh, &sl);
        int mh = (unsigned short)sh, ml = (unsigned short)sl;
        int nh = __shfl_down(mh, 1), nl = __shfl_down(ml, 1);
        short* dh = lay ? h1bh : (h0bh + 4096);
        short* dl = lay ? h1bl : (h0bl + 4096);
        if (!(jl & 1)) {
            st_a((int*)dh + ((bb * 256 + j) >> 1), mh | (nh << 16));
            st_a((int*)dl + ((bb * 256 + j) >> 1), ml | (nl << 16));
        }
    }
    int gen = 0;
    gbar(flags, ++gen);

    int lane = tid & 63, w = tid >> 6, cc = lane & 15, g4 = lane >> 4, koff = g4 * 8;
    int tw = w & 1, kb = (w >> 1) * 128;
    int off = ((cc << 8) + kb + koff) >> 2;        // u64 index into a 4096-short plane
    int wr = (tw * 16 + cc) * KP + kb + koff;

    for (int i = 0; i <= SEQ; ++i) {
        int rb = (i + 1) & 1, wb = i & 1;
        bool actL0 = (i < SEQ), actL1 = (i >= 1);

        // rotate gates prefetch (valid: previous gbar drained vmcnt)
        float gpre[4];
#pragma unroll
        for (int q = 0; q < 4; ++q) { TOUCHF(gnew[q]); gpre[q] = gnew[q]; }

        // -------- hoisted LLC loads: issue everything, then wait once --------
        u64 a0h[8], a0l[8], a1h[8], a1l[8];
        {
            const u64* p0h = (const u64*)(h0bh + rb * 4096) + off;
            const u64* p0l = (const u64*)(h0bl + rb * 4096) + off;
#pragma unroll
            for (int ki = 0; ki < 4; ++ki) {
                a0h[2*ki] = ld8(p0h + ki*8); a0h[2*ki+1] = ld8(p0h + ki*8 + 1);
                a0l[2*ki] = ld8(p0l + ki*8); a0l[2*ki+1] = ld8(p0l + ki*8 + 1);
            }
            if (actL1) {
                const u64* p1h = (const u64*)(h1bh + rb * 4096) + off;
                const u64* p1l = (const u64*)(h1bl + rb * 4096) + off;
#pragma unroll
                for (int ki = 0; ki < 4; ++ki) {
                    a1h[2*ki] = ld8(p1h + ki*8); a1h[2*ki+1] = ld8(p1h + ki*8 + 1);
                    a1l[2*ki] = ld8(p1l + ki*8); a1l[2*ki+1] = ld8(p1l + ki*8 + 1);
                }
            }
        }
        asm volatile("s_waitcnt vmcnt(0)" ::: "memory");
        __builtin_amdgcn_sched_barrier(0);

        // prefetch NEXT step's x-side gates (consumed next iteration after gbar)
        if (!lay && i + 1 < SEQ) {
#pragma unroll
            for (int q = 0; q < 4; ++q)
                gnew[q] = lddw(&gates0[(long)((i + 1) * BB + bb) * GG + q * 256 + j]);
        }

        f32x4 z = {0.f, 0.f, 0.f, 0.f};
        f32x4 s0 = z, s1 = z;
        if (actL0) {            // L0 tile tw, K-half kb
            f32x4 a1 = z, a2 = z;
#pragma unroll
            for (int ki = 0; ki < 4; ++ki) {
                short8 ah = mk8(a0h[2*ki], a0h[2*ki+1]);
                short8 al = mk8(a0l[2*ki], a0l[2*ki+1]);
                TOUCH8(ah); TOUCH8(al);
                short8 wh  = *(const short8*)(Wl[0] + wr + ki * 32);
                short8 wl2 = *(const short8*)(Wl[1] + wr + ki * 32);
                a1 = MFMA(ah, wh, a1);
                a2 = MFMA(ah, wl2, a2);
                a2 = MFMA(al, wh, a2);
            }
            s0 = a1 + a2;
        }
        if (actL1) {            // L1 tile tw; x = h0(prev) (reuse a0 regs)
            f32x4 a1 = z, a2 = z;
#pragma unroll
            for (int ki = 0; ki < 4; ++ki) {
                short8 xh = mk8(a0h[2*ki], a0h[2*ki+1]);
                short8 xl = mk8(a0l[2*ki], a0l[2*ki+1]);
                short8 hh = mk8(a1h[2*ki], a1h[2*ki+1]);
                short8 hl = mk8(a1l[2*ki], a1l[2*ki+1]);
                TOUCH8(xh); TOUCH8(xl); TOUCH8(hh); TOUCH8(hl);
                a1 = MFMA(xh, *(const short8*)(Wl[2] + wr + ki * 32), a1);
                a2 = MFMA(xh, *(const short8*)(Wl[3] + wr + ki * 32), a2);
                a2 = MFMA(xl, *(const short8*)(Wl[2] + wr + ki * 32), a2);
                a1 = MFMA(hh, *(const short8*)(Wl[4] + wr + ki * 32), a1);
                a2 = MFMA(hh, *(const short8*)(Wl[5] + wr + ki * 32), a2);
                a2 = MFMA(hl, *(const short8*)(Wl[4] + wr + ki * 32), a2);
            }
            s1 = a1 + a2;
        }
#pragma unroll
        for (int r = 0; r < 4; ++r) {
            gacc[w][g4 * 4 + r][cc] = s0[r];
            gacc[4 + w][g4 * 4 + r][cc] = s1[r];
        }
        __syncthreads();

        bool act = lay ? actL1 : actL0;
        if (act) {
            int t = lay ? (i - 1) : i;
            float gv[4];
#pragma unroll
            for (int q = 0; q < 4; ++q) {
                int lr = q * 8 + jl, tl = lr >> 4, c = lr & 15;
                gv[q] = lay ? (gacc[4 + tl][bb][c] + gacc[6 + tl][bb][c] + bs[q])
                            : (gacc[tl][bb][c] + gacc[2 + tl][bb][c] + gpre[q]);
            }
            float c = sigm(gv[1]) * creg + sigm(gv[0]) * tanh_f(gv[2]);
            creg = c;
            float h = sigm(gv[3]) * tanh_f(c);
            short sh, sl; split2s(h, &sh, &sl);
            int mh = (unsigned short)sh, ml = (unsigned short)sl;
            int nh = __shfl_down(mh, 1), nl = __shfl_down(ml, 1);
            short* dh = (lay ? h1bh : h0bh) + wb * 4096;
            short* dl = (lay ? h1bl : h0bl) + wb * 4096;
            if (!(jl & 1)) {
                st_a((int*)dh + ((bb * 256 + j) >> 1), mh | (nh << 16));
                st_a((int*)dl + ((bb * 256 + j) >> 1), ml | (nl << 16));
            }
            if (t == SEQ - 1) hfin[lay * 4096 + bb * 256 + j] = h;
        }
        gbar(flags, ++gen);
    }
}

// ---------------- decoder: 2 phases/step; h-operands passed in registers ----------------
// Phase A(t): x = h1[t-1] (fresh load), h = h0[t-1] = prev phase B's x regs.
// Phase B(t): x = h0[t]   (fresh load), h = h1[t-1] = this phase A's x regs.
__global__ void __launch_bounds__(256, 1) k_dec_coop(
        const short* __restrict__ Wihh, const short* __restrict__ Wihl,   // [2][1024][256]
        const short* __restrict__ Whhh, const short* __restrict__ Whhl,
        const float* __restrict__ dbih, const float* __restrict__ dbhh,   // [2][1024]
        const float* __restrict__ tef, const float* __restrict__ hfin,
        short* __restrict__ h0bh, short* __restrict__ h0bl,   // [2][4096]
        short* __restrict__ h1bh, short* __restrict__ h1bl,
        short* __restrict__ teh, short* __restrict__ tel,     // [4096] init bufs
        short* __restrict__ h0ih, short* __restrict__ h0il,
        short* __restrict__ h1ih, short* __restrict__ h1il,
        float* __restrict__ preds, int* __restrict__ flags) {
    __shared__ short Wl[8][32 * KP];
    __shared__ float gacc[4][16][17];
    const int WN = GG * EE;

    int tid = threadIdx.x;
    int j0 = blockIdx.x * 8;
    load_wslice(Wihh, j0, Wl[0]);      load_wslice(Wihl, j0, Wl[1]);
    load_wslice(Whhh, j0, Wl[2]);      load_wslice(Whhl, j0, Wl[3]);
    load_wslice(Wihh + WN, j0, Wl[4]); load_wslice(Wihl + WN, j0, Wl[5]);
    load_wslice(Whhh + WN, j0, Wl[6]); load_wslice(Whhl + WN, j0, Wl[7]);

    int bb = (tid & 127) >> 3, jl = tid & 7, j = j0 + jl;
    float c0r = 0.f, c1r = 0.f;
    float bs0[4] = {0,0,0,0}, bs1[4] = {0,0,0,0};
    if (tid < 128) {
        float h0v = hfin[bb * 256 + j], h1v = hfin[4096 + bb * 256 + j];
        c0r = h0v; c1r = h1v;                      // source bug: c := h
        short sh, sl;
        int idx = (bb * 256 + j) >> 1;
        split2s(tef[j], &sh, &sl);
        {
            int mh = (unsigned short)sh, ml = (unsigned short)sl;
            int nh = __shfl_down(mh, 1), nl = __shfl_down(ml, 1);
            if (!(jl & 1)) { st_a((int*)teh + idx, mh | (nh << 16));
                             st_a((int*)tel + idx, ml | (nl << 16)); }
        }
        split2s(h0v, &sh, &sl);
        {
            int mh = (unsigned short)sh, ml = (unsigned short)sl;
            int nh = __shfl_down(mh, 1), nl = __shfl_down(ml, 1);
            if (!(jl & 1)) { st_a((int*)h0ih + idx, mh | (nh << 16));
                             st_a((int*)h0il + idx, ml | (nl << 16)); }
        }
        split2s(h1v, &sh, &sl);
        {
            int mh = (unsigned short)sh, ml = (unsigned short)sl;
            int nh = __shfl_down(mh, 1), nl = __shfl_down(ml, 1);
            if (!(jl & 1)) { st_a((int*)h1ih + idx, mh | (nh << 16));
                             st_a((int*)h1il + idx, ml | (nl << 16)); }
        }
#pragma unroll
        for (int q = 0; q < 4; ++q) {
            bs0[q] = dbih[q*256+j] + dbhh[q*256+j];
            bs1[q] = dbih[GG + q*256+j] + dbhh[GG + q*256+j];
        }
    }
    int gen = 0;
    gbar(flags, ++gen);

    int lane = tid & 63, w = tid >> 6, cc = lane & 15, g4 = lane >> 4, koff = g4 * 8;
    int tw = w & 1, kb = (w >> 1) * 128;       // tile / K-half per wave
    int off = ((cc << 8) + kb + koff) >> 2;    // u64 index
    int wr = (tw * 16 + cc) * KP + kb + koff;

    // persistent x-fragment registers (double duty as next phase's h-operand)
    u64 xAh[8], xAl[8], xBh[8], xBl[8], h1i_h[8], h1i_l[8];

    // pre-load: xB := h0-init (serves as phase-A(0) h-operand); h1i := h1-init
    {
        const u64* p0h = (const u64*)h0ih + off;
        const u64* p0l = (const u64*)h0il + off;
        const u64* p1h = (const u64*)h1ih + off;
        const u64* p1l = (const u64*)h1il + off;
#pragma unroll
        for (int ki = 0; ki < 4; ++ki) {
            xBh[2*ki] = ld8(p0h + ki*8); xBh[2*ki+1] = ld8(p0h + ki*8 + 1);
            xBl[2*ki] = ld8(p0l + ki*8); xBl[2*ki+1] = ld8(p0l + ki*8 + 1);
            h1i_h[2*ki] = ld8(p1h + ki*8); h1i_h[2*ki+1] = ld8(p1h + ki*8 + 1);
            h1i_l[2*ki] = ld8(p1l + ki*8); h1i_l[2*ki+1] = ld8(p1l + ki*8 + 1);
        }
    }

    for (int t = 0; t < TT - 1; ++t) {
        int pb = (t - 1) & 1;
        // ---- phase A: layer 0 : x = h1(t-1) fresh, h = h0(t-1) in xB regs ----
        {
            const u64* pxh = (const u64*)(t ? h1bh + pb * 4096 : teh) + off;
            const u64* pxl = (const u64*)(t ? h1bl + pb * 4096 : tel) + off;
#pragma unroll
            for (int ki = 0; ki < 4; ++ki) {
                xAh[2*ki] = ld8(pxh + ki*8); xAh[2*ki+1] = ld8(pxh + ki*8 + 1);
                xAl[2*ki] = ld8(pxl + ki*8); xAl[2*ki+1] = ld8(pxl + ki*8 + 1);
            }
            asm volatile("s_waitcnt vmcnt(0)" ::: "memory");
            __builtin_amdgcn_sched_barrier(0);
            f32x4 a1 = {0.f,0.f,0.f,0.f}, a2 = {0.f,0.f,0.f,0.f};
#pragma unroll
            for (int ki = 0; ki < 4; ++ki) {
                short8 a = mk8(xAh[2*ki], xAh[2*ki+1]), b = mk8(xAl[2*ki], xAl[2*ki+1]);
                short8 c = mk8(xBh[2*ki], xBh[2*ki+1]), d = mk8(xBl[2*ki], xBl[2*ki+1]);
                TOUCH8(a); TOUCH8(b); TOUCH8(c); TOUCH8(d);
                a1 = MFMA(a, *(const short8*)(Wl[0] + wr + ki * 32), a1);
                a2 = MFMA(a, *(const short8*)(Wl[1] + wr + ki * 32), a2);
                a2 = MFMA(b, *(const short8*)(Wl[0] + wr + ki * 32), a2);
                a1 = MFMA(c, *(const short8*)(Wl[2] + wr + ki * 32), a1);
                a2 = MFMA(c, *(const short8*)(Wl[3] + wr + ki * 32), a2);
                a2 = MFMA(d, *(const short8*)(Wl[2] + wr + ki * 32), a2);
            }
            f32x4 accs = a1 + a2;
#pragma unroll
            for (int r = 0; r < 4; ++r) gacc[w][g4 * 4 + r][cc] = accs[r];
        }
        __syncthreads();
        if (tid < 128) {
            float gv[4];
#pragma unroll
            for (int q = 0; q < 4; ++q) {
                int lr = q * 8 + jl;
                gv[q] = gacc[lr >> 4][bb][lr & 15] + gacc[2 + (lr >> 4)][bb][lr & 15] + bs0[q];
            }
            float c = sigm(gv[1]) * c0r + sigm(gv[0]) * tanh_f(gv[2]);
            c0r = c;
            float h = sigm(gv[3]) * tanh_f(c);
            short sh, sl; split2s(h, &sh, &sl);
            int mh = (unsigned short)sh, ml = (unsigned short)sl;
            int nh = __shfl_down(mh, 1), nl = __shfl_down(ml, 1);
            if (!(jl & 1)) {
                int idx = (bb * 256 + j) >> 1;
                st_a((int*)h0bh + (t & 1) * 2048 + idx, mh | (nh << 16));
                st_a((int*)h0bl + (t & 1) * 2048 + idx, ml | (nl << 16));
            }
        }
        gbar(flags, ++gen);
        // ---- phase B: layer 1 : x = h0(t) fresh, h = h1(t-1) in xA regs (or h1-init) ----
        {
            const u64* pxh = (const u64*)(h0bh + (t & 1) * 4096) + off;
            const u64* pxl = (const u64*)(h0bl + (t & 1) * 4096) + off;
#pragma unroll
            for (int ki = 0; ki < 4; ++ki) {
                xBh[2*ki] = ld8(pxh + ki*8); xBh[2*ki+1] = ld8(pxh + ki*8 + 1);
                xBl[2*ki] = ld8(pxl + ki*8); xBl[2*ki+1] = ld8(pxl + ki*8 + 1);
            }
            asm volatile("s_waitcnt vmcnt(0)" ::: "memory");
            __builtin_amdgcn_sched_barrier(0);
            f32x4 a1 = {0.f,0.f,0.f,0.f}, a2 = {0.f,0.f,0.f,0.f};
#pragma unroll
            for (int ki = 0; ki < 4; ++ki) {
                short8 a = mk8(xBh[2*ki], xBh[2*ki+1]), b = mk8(xBl[2*ki], xBl[2*ki+1]);
                u64 hhq0 = t ? xAh[2*ki] : h1i_h[2*ki];
                u64 hhq1 = t ? xAh[2*ki+1] : h1i_h[2*ki+1];
                u64 hlq0 = t ? xAl[2*ki] : h1i_l[2*ki];
                u64 hlq1 = t ? xAl[2*ki+1] : h1i_l[2*ki+1];
                short8 c = mk8(hhq0, hhq1), d = mk8(hlq0, hlq1);
                TOUCH8(a); TOUCH8(b); TOUCH8(c); TOUCH8(d);
                a1 = MFMA(a, *(const short8*)(Wl[4] + wr + ki * 32), a1);
                a2 = MFMA(a, *(const short8*)(Wl[5] + wr + ki * 32), a2);
                a2 = MFMA(b, *(const short8*)(Wl[4] + wr + ki * 32), a2);
                a1 = MFMA(c, *(const short8*)(Wl[6] + wr + ki * 32), a1);
                a2 = MFMA(c, *(const short8*)(Wl[7] + wr + ki * 32), a2);
                a2 = MFMA(d, *(const short8*)(Wl[6] + wr + ki * 32), a2);
            }
            f32x4 accs = a1 + a2;
#pragma unroll
            for (int r = 0; r < 4; ++r) gacc[w][g4 * 4 + r][cc] = accs[r];
        }
        __syncthreads();
        if (tid < 128) {
            float gv[4];
#pragma unroll
            for (int q = 0; q < 4; ++q) {
                int lr = q * 8 + jl;
                gv[q] = gacc[lr >> 4][bb][lr & 15] + gacc[2 + (lr >> 4)][bb][lr & 15] + bs1[q];
            }
            float c = sigm(gv[1]) * c1r + sigm(gv[0]) * tanh_f(gv[2]);
            c1r = c;
            float h = sigm(gv[3]) * tanh_f(c);
            short sh, sl; split2s(h, &sh, &sl);
            int mh = (unsigned short)sh, ml = (unsigned short)sl;
            int nh = __shfl_down(mh, 1), nl = __shfl_down(ml, 1);
            if (!(jl & 1)) {
                int idx = (bb * 256 + j) >> 1;
                st_a((int*)h1bh + (t & 1) * 2048 + idx, mh | (nh << 16));
                st_a((int*)h1bl + (t & 1) * 2048 + idx, ml | (nl << 16));
            }
            preds[((long)(t + 1) * BB + bb) * HH + j] = h;
        }
        gbar(flags, ++gen);
    }
}

// ---------------- host launch ----------------
extern "C" void kernel_launch(void* const* d_in, const int* in_sizes, int n_in,
                              void* d_out, int out_size, void* d_ws, size_t ws_size,
                              hipStream_t stream) {
    const int*   src   = (const int*)  d_in[0];
    const float* te    = (const float*)d_in[2];
    const float* h0    = (const float*)d_in[3];
    const float* c0    = (const float*)d_in[4];
    const float* table = (const float*)d_in[5];
    const float* eWih  = (const float*)d_in[6];
    const float* eWhh  = (const float*)d_in[7];
    const float* ebih  = (const float*)d_in[8];
    const float* ebhh  = (const float*)d_in[9];
    const float* dWih  = (const float*)d_in[10];
    const float* dWhh  = (const float*)d_in[11];
    const float* dbih  = (const float*)d_in[12];
    const float* dbhh  = (const float*)d_in[13];
    float* preds = (float*)d_out;

    const int WN = GG * EE;                  // 262144 elems per layer-matrix
    const size_t MB = 1u << 20;
    char* ws = (char*)d_ws;
    short* eWih_hi = (short*)(ws + 0 * MB);
    short* eWih_lo = (short*)(ws + 1 * MB);
    short* eWhh_hi = (short*)(ws + 2 * MB);
    short* eWhh_lo = (short*)(ws + 3 * MB);
    short* dWih_hi = (short*)(ws + 4 * MB);
    short* dWih_lo = (short*)(ws + 5 * MB);
    short* dWhh_hi = (short*)(ws + 6 * MB);
    short* dWhh_lo = (short*)(ws + 7 * MB);
    short* Xa_hi   = (short*)(ws + 8 * MB);      // [4096,256]
    short* Xa_lo   = (short*)(ws + 10 * MB);
    float* hfin    = (float*)(ws + 12 * MB);     // [2,16,256]
    int*   ctrl    = (int*)  (ws + 12 * MB + (64 << 10));   // 1024 spaced flag words
    short* eb      = (short*)(ws + 12 * MB + (128 << 10));  // enc h bufs 4x8192
    short* db      = (short*)(ws + 12 * MB + (256 << 10));  // dec bufs
    float* gates0  = (float*)(ws + 16 * MB);     // [4096,1024] f32

    int* flags_enc = ctrl;          // 32 blocks x 16-int spacing
    int* flags_dec = ctrl + 512;

    k_binit<<<1, 1024, 0, stream>>>(ctrl);

    k_cvt2<<<2048, 256, 0, stream>>>(eWih, (__hip_bfloat16*)eWih_hi, (__hip_bfloat16*)eWih_lo, 2 * WN);
    k_cvt2<<<2048, 256, 0, stream>>>(eWhh, (__hip_bfloat16*)eWhh_hi, (__hip_bfloat16*)eWhh_lo, 2 * WN);
    k_cvt2<<<2048, 256, 0, stream>>>(dWih, (__hip_bfloat16*)dWih_hi, (__hip_bfloat16*)dWih_lo, 2 * WN);
    k_cvt2<<<2048, 256, 0, stream>>>(dWhh, (__hip_bfloat16*)dWhh_hi, (__hip_bfloat16*)dWhh_lo, 2 * WN);

    // encoder L0 input-side GEMM (parallel), then cooperative 2-layer wavefront scan
    k_embed<<<4096, 256, 0, stream>>>(src, table, (__hip_bfloat16*)Xa_hi, (__hip_bfloat16*)Xa_lo);
    k_gemm_in<<<4096, 256, 0, stream>>>((__hip_bfloat16*)Xa_hi, (__hip_bfloat16*)Xa_lo,
                                        (__hip_bfloat16*)eWih_hi, (__hip_bfloat16*)eWih_lo,
                                        ebih, ebhh, gates0);
    k_enc_coop<<<NWG, 256, 0, stream>>>(gates0, eWhh_hi, eWhh_lo,
                                        eWih_hi + WN, eWih_lo + WN, eWhh_hi + WN, eWhh_lo + WN,
                                        ebih + GG, ebhh + GG, h0, c0,
                                        eb, eb + 8192, eb + 16384, eb + 24576,
                                        hfin, flags_enc);

    // decoder cooperative scan
    k_dec_coop<<<NWG, 256, 0, stream>>>(dWih_hi, dWih_lo, dWhh_hi, dWhh_lo,
                                        dbih, dbhh, te, hfin,
                                        db, db + 8192, db + 16384, db + 24576,
                                        db + 32768, db + 36864, db + 40960, db + 45056,
                                        db + 49152, db + 53248,
                                        preds, flags_dec);

    // predictions[0] = 0
    k_zero<<<16, 256, 0, stream>>>(preds);
}

// Round 8
// 2309.821 us; speedup vs baseline: 2.3063x; 1.1738x over previous
//
#include <hip/hip_runtime.h>
#include <hip/hip_bf16.h>

typedef __attribute__((ext_vector_type(8))) short short8;
typedef __attribute__((ext_vector_type(4))) float f32x4;

#define SEQ   256   // source length S
#define BB    16    // batch
#define EE    256   // embed dim
#define HH    256   // hidden
#define GG    1024  // 4*H
#define TT    128   // target_size
#define NWG   32    // persistent workgroups
#define KP    264   // LDS row stride in shorts
#define SLOT_S 8192 // shorts per h slot: 16 rows x 32 chunks x 16 (8 hi | 8 lo)
#define SENT  0xFF80FF80u   // packed bf16 [-inf|-inf]: unreachable for finite h
#define MAXTRY (1 << 20)

__device__ __forceinline__ float sigm(float x) { return 1.0f / (1.0f + __expf(-x)); }
__device__ __forceinline__ float tanh_f(float x) {
    float e = __expf(2.0f * x);
    return 1.0f - 2.0f / (e + 1.0f);
}
__device__ __forceinline__ void split2s(float v, short* hi, short* lo) {
    __hip_bfloat16 h = __float2bfloat16(v);
    __hip_bfloat16 l = __float2bfloat16(v - __bfloat162float(h));
    *hi = *(short*)&h; *lo = *(short*)&l;
}
__device__ __forceinline__ f32x4 MFMA(short8 a, short8 b, f32x4 c) {
    return __builtin_amdgcn_mfma_f32_16x16x32_bf16(a, b, c, 0, 0, 0);
}

// ---- LLC-direct accesses (sc0 sc1): bypass L1/L2, served at the coherence point ----
__device__ __forceinline__ short8 ld16s(const short* p) {
    short8 r;
    asm volatile("global_load_dwordx4 %0, %1, off sc0 sc1" : "=v"(r) : "v"(p));
    return r;   // valid only after vmwait()
}
__device__ __forceinline__ void st4s(int* p, int v) {
    asm volatile("global_store_dword %0, %1, off sc0 sc1" :: "v"(p), "v"(v) : "memory");
}
__device__ __forceinline__ void vmwait() {
    asm volatile("s_waitcnt vmcnt(0)" ::: "memory");
    __builtin_amdgcn_sched_barrier(0);
}
union U8 { short8 s; unsigned u[4]; };
__device__ __forceinline__ unsigned chk(short8 f) {
    U8 x; x.s = f;
    return (unsigned)((x.u[0] == SENT) | (x.u[1] == SENT) | (x.u[2] == SENT) | (x.u[3] == SENT));
}

// ---------------- utility kernels ----------------
__global__ void k_sent(unsigned* p) {   // fill slot region with sentinel, 16B/thread
    long i = ((long)blockIdx.x * 256 + threadIdx.x) * 4;
    p[i] = SENT; p[i + 1] = SENT; p[i + 2] = SENT; p[i + 3] = SENT;
}

__global__ void k_cvt2(const float* __restrict__ s, __hip_bfloat16* __restrict__ hi,
                       __hip_bfloat16* __restrict__ lo, int n) {
    int i = blockIdx.x * 256 + threadIdx.x;
    if (i < n) {
        short a, b; split2s(s[i], &a, &b);
        hi[i] = *(__hip_bfloat16*)&a; lo[i] = *(__hip_bfloat16*)&b;
    }
}

__global__ void k_zero(float* __restrict__ p) {
    p[blockIdx.x * 256 + threadIdx.x] = 0.0f;
}

__global__ void k_embed(const int* __restrict__ src, const float* __restrict__ tab,
                        __hip_bfloat16* __restrict__ xhi, __hip_bfloat16* __restrict__ xlo) {
    int r = blockIdx.x;
    int j = threadIdx.x;
    long idx = src[r];
    short a, b; split2s(tab[idx * EE + j], &a, &b);
    xhi[(long)r * EE + j] = *(__hip_bfloat16*)&a;
    xlo[(long)r * EE + j] = *(__hip_bfloat16*)&b;
}

// ------------- input-side GEMM: gates0 = X @ Wih0^T + bih0 + bhh0 -------------
__global__ void __launch_bounds__(256) k_gemm_in(
        const __hip_bfloat16* __restrict__ Xhi, const __hip_bfloat16* __restrict__ Xlo,
        const __hip_bfloat16* __restrict__ Whi, const __hip_bfloat16* __restrict__ Wlo,
        const float* __restrict__ bih, const float* __restrict__ bhh,
        float* __restrict__ gates) {
    int lane = threadIdx.x & 63, w = threadIdx.x >> 6;
    int m0 = (blockIdx.x >> 4) * 16;
    int n0 = ((blockIdx.x & 15) * 4 + w) * 16;
    int cc = lane & 15, g = lane >> 4;
    int koff = g * 8;
    const short* xh = (const short*)Xhi + (long)(m0 + cc) * EE + koff;
    const short* xl = (const short*)Xlo + (long)(m0 + cc) * EE + koff;
    const short* wh = (const short*)Whi + (long)(n0 + cc) * EE + koff;
    const short* wl = (const short*)Wlo + (long)(n0 + cc) * EE + koff;
    f32x4 acc1 = {0.f, 0.f, 0.f, 0.f}, acc2 = {0.f, 0.f, 0.f, 0.f};
#pragma unroll
    for (int k = 0; k < EE; k += 32) {
        short8 ah = *(const short8*)(xh + k), al = *(const short8*)(xl + k);
        short8 bh = *(const short8*)(wh + k), bl = *(const short8*)(wl + k);
        acc1 = MFMA(ah, bh, acc1);
        acc2 = MFMA(ah, bl, acc2);
        acc2 = MFMA(al, bh, acc2);
    }
    f32x4 acc = acc1 + acc2;
    int ncol = n0 + cc;
    float bias = bih[ncol] + bhh[ncol];
    int mrow = m0 + g * 4;
#pragma unroll
    for (int r = 0; r < 4; ++r)
        gates[(long)(mrow + r) * GG + ncol] = acc[r] + bias;
}

// ---- gather one 32-row weight slice into LDS ----
__device__ __forceinline__ void load_wslice(const short* __restrict__ Wg, int j0,
                                            short* __restrict__ Wl) {
    int tid = threadIdx.x;
    int lr = tid >> 3;
    int q = lr >> 3, jl = lr & 7;
    const short* src = Wg + (long)(q * 256 + j0 + jl) * 256;
    short* dst = Wl + lr * KP;
#pragma unroll
    for (int s = 0; s < 4; ++s) {
        int c = (tid & 7) * 8 + s * 64;
        *(short8*)(dst + c) = *(const short8*)(src + c);
    }
}

// slot layout: [row 0..15][chunk 0..31][8 hi shorts | 8 lo shorts]; chunk c = j/8
// producer (bb,j) hi-pair int index: bb*256 + (j>>3)*8 + ((j&7)>>1), lo at +4

// ---------------- encoder: dataflow wavefront, no barriers ----------------
__global__ void __launch_bounds__(256, 1) k_enc_coop(
        const float* __restrict__ gates0,
        const short* __restrict__ Whh0h, const short* __restrict__ Whh0l,
        const short* __restrict__ Wih1h, const short* __restrict__ Wih1l,
        const short* __restrict__ Whh1h, const short* __restrict__ Whh1l,
        const float* __restrict__ bih1, const float* __restrict__ bhh1,
        const float* __restrict__ h0p, const float* __restrict__ c0p,
        short* __restrict__ H0, short* __restrict__ H1,    // [257][SLOT_S]
        float* __restrict__ hfin) {
    __shared__ short Wl[6][32 * KP];
    __shared__ float gacc[2][8][16][17];

    int tid = threadIdx.x, bid = blockIdx.x;
    int j0 = bid * 8;
    load_wslice(Whh0h, j0, Wl[0]); load_wslice(Whh0l, j0, Wl[1]);
    load_wslice(Wih1h, j0, Wl[2]); load_wslice(Wih1l, j0, Wl[3]);
    load_wslice(Whh1h, j0, Wl[4]); load_wslice(Whh1l, j0, Wl[5]);

    int bb = (tid & 127) >> 3, jl = tid & 7, j = j0 + jl, lay = tid >> 7;
    float creg = c0p[lay * 4096 + bb * 256 + j];
    float bs[4] = {0.f, 0.f, 0.f, 0.f};
    if (lay) {
#pragma unroll
        for (int q = 0; q < 4; ++q) bs[q] = bih1[q * 256 + j] + bhh1[q * 256 + j];
    }
    {   // init: state slot 0
        float hv = h0p[lay * 4096 + bb * 256 + j];
        short sh, sl; split2s(hv, &sh, &sl);
        int mh = (unsigned short)sh, ml = (unsigned short)sl;
        int nh = __shfl_down(mh, 1), nl = __shfl_down(ml, 1);
        int* dst = (int*)(lay ? H1 : H0);
        if (!(jl & 1)) {
            int idx = bb * 256 + bid * 8 + (jl >> 1);
            st4s(dst + idx, mh | (nh << 16));
            st4s(dst + idx + 4, ml | (nl << 16));
        }
    }

    int lane = tid & 63, w = tid >> 6, cc = lane & 15, g4 = lane >> 4, koff = g4 * 8;
    int tw = w & 1, kb = (w >> 1) * 128;
    int abase = cc * 512 + kb * 2 + g4 * 16;       // shorts into a slot
    int wr = (tw * 16 + cc) * KP + kb + koff;

    for (int i = 0; i <= SEQ; ++i) {
        bool actL0 = (i < SEQ), actL1 = (i >= 1);
        int par = i & 1;

        float gpre[4];
        if (!lay && actL0) {
#pragma unroll
            for (int q = 0; q < 4; ++q)
                gpre[q] = gates0[(long)(i * BB + bb) * GG + q * 256 + j];
        }

        // ---- dataflow poll: load h0 slot i (always; L1's x) and h1 slot i-1 ----
        short8 f0h[4], f0l[4], f1h[4], f1l[4];
        const short* b0 = H0 + (long)i * SLOT_S + abase;
        const short* b1 = H1 + (long)(i - 1) * SLOT_S + abase;
        int tries = 0;
        while (true) {
#pragma unroll
            for (int ki = 0; ki < 4; ++ki) {
                f0h[ki] = ld16s(b0 + ki * 64);
                f0l[ki] = ld16s(b0 + ki * 64 + 8);
            }
            if (actL1) {
#pragma unroll
                for (int ki = 0; ki < 4; ++ki) {
                    f1h[ki] = ld16s(b1 + ki * 64);
                    f1l[ki] = ld16s(b1 + ki * 64 + 8);
                }
            }
            vmwait();
            unsigned bad = 0;
#pragma unroll
            for (int ki = 0; ki < 4; ++ki) bad |= chk(f0h[ki]) | chk(f0l[ki]);
            if (actL1) {
#pragma unroll
                for (int ki = 0; ki < 4; ++ki) bad |= chk(f1h[ki]) | chk(f1l[ki]);
            }
            if (!__any((int)bad) || ++tries > MAXTRY) break;
        }

        f32x4 z = {0.f, 0.f, 0.f, 0.f};
        f32x4 s0 = z, s1 = z;
        if (actL0) {
            f32x4 a1 = z, a2 = z;
#pragma unroll
            for (int ki = 0; ki < 4; ++ki) {
                short8 wh  = *(const short8*)(Wl[0] + wr + ki * 32);
                short8 wl2 = *(const short8*)(Wl[1] + wr + ki * 32);
                a1 = MFMA(f0h[ki], wh, a1);
                a2 = MFMA(f0h[ki], wl2, a2);
                a2 = MFMA(f0l[ki], wh, a2);
            }
            s0 = a1 + a2;
        }
        if (actL1) {
            f32x4 a1 = z, a2 = z;
#pragma unroll
            for (int ki = 0; ki < 4; ++ki) {
                a1 = MFMA(f0h[ki], *(const short8*)(Wl[2] + wr + ki * 32), a1);
                a2 = MFMA(f0h[ki], *(const short8*)(Wl[3] + wr + ki * 32), a2);
                a2 = MFMA(f0l[ki], *(const short8*)(Wl[2] + wr + ki * 32), a2);
                a1 = MFMA(f1h[ki], *(const short8*)(Wl[4] + wr + ki * 32), a1);
                a2 = MFMA(f1h[ki], *(const short8*)(Wl[5] + wr + ki * 32), a2);
                a2 = MFMA(f1l[ki], *(const short8*)(Wl[4] + wr + ki * 32), a2);
            }
            s1 = a1 + a2;
        }
#pragma unroll
        for (int r = 0; r < 4; ++r) {
            gacc[par][w][g4 * 4 + r][cc] = s0[r];
            gacc[par][4 + w][g4 * 4 + r][cc] = s1[r];
        }
        __syncthreads();

        bool act = lay ? actL1 : actL0;
        if (act) {
            int t = lay ? (i - 1) : i;
            float gv[4];
#pragma unroll
            for (int q = 0; q < 4; ++q) {
                int lr = q * 8 + jl, tl = lr >> 4, c = lr & 15;
                gv[q] = lay ? (gacc[par][4 + tl][bb][c] + gacc[par][6 + tl][bb][c] + bs[q])
                            : (gacc[par][tl][bb][c] + gacc[par][2 + tl][bb][c] + gpre[q]);
            }
            float c = sigm(gv[1]) * creg + sigm(gv[0]) * tanh_f(gv[2]);
            creg = c;
            float h = sigm(gv[3]) * tanh_f(c);
            short sh, sl; split2s(h, &sh, &sl);
            int mh = (unsigned short)sh, ml = (unsigned short)sl;
            int nh = __shfl_down(mh, 1), nl = __shfl_down(ml, 1);
            int* dst = (int*)(lay ? (H1 + (long)i * SLOT_S) : (H0 + (long)(i + 1) * SLOT_S));
            if (!(jl & 1)) {
                int idx = bb * 256 + bid * 8 + (jl >> 1);
                st4s(dst + idx, mh | (nh << 16));
                st4s(dst + idx + 4, ml | (nl << 16));
            }
            if (t == SEQ - 1) hfin[lay * 4096 + bb * 256 + j] = h;
        }
    }
}

// ---------------- decoder: dataflow, 2 phases/step, register h-handoff ----------------
__global__ void __launch_bounds__(256, 1) k_dec_coop(
        const short* __restrict__ Wihh, const short* __restrict__ Wihl,
        const short* __restrict__ Whhh, const short* __restrict__ Whhl,
        const float* __restrict__ dbih, const float* __restrict__ dbhh,
        const float* __restrict__ tef, const float* __restrict__ hfin,
        short* __restrict__ H0, short* __restrict__ H1,    // [128][SLOT_S]
        short* __restrict__ TE,                            // [SLOT_S]
        float* __restrict__ preds) {
    __shared__ short Wl[8][32 * KP];
    __shared__ float gacc[2][4][16][17];
    const int WN = GG * EE;

    int tid = threadIdx.x, bid = blockIdx.x;
    int j0 = bid * 8;
    load_wslice(Wihh, j0, Wl[0]);      load_wslice(Wihl, j0, Wl[1]);
    load_wslice(Whhh, j0, Wl[2]);      load_wslice(Whhl, j0, Wl[3]);
    load_wslice(Wihh + WN, j0, Wl[4]); load_wslice(Wihl + WN, j0, Wl[5]);
    load_wslice(Whhh + WN, j0, Wl[6]); load_wslice(Whhl + WN, j0, Wl[7]);

    int bb = (tid & 127) >> 3, jl = tid & 7, j = j0 + jl;
    float c0r = 0.f, c1r = 0.f;
    float bs0[4] = {0,0,0,0}, bs1[4] = {0,0,0,0};
    if (tid < 128) {
        float h0v = hfin[bb * 256 + j], h1v = hfin[4096 + bb * 256 + j];
        c0r = h0v; c1r = h1v;                      // source bug: c := h
        int idx = bb * 256 + bid * 8 + (jl >> 1);
        short sh, sl;
        split2s(tef[j], &sh, &sl);
        {
            int mh = (unsigned short)sh, ml = (unsigned short)sl;
            int nh = __shfl_down(mh, 1), nl = __shfl_down(ml, 1);
            if (!(jl & 1)) { st4s((int*)TE + idx, mh | (nh << 16));
                             st4s((int*)TE + idx + 4, ml | (nl << 16)); }
        }
        split2s(h0v, &sh, &sl);
        {
            int mh = (unsigned short)sh, ml = (unsigned short)sl;
            int nh = __shfl_down(mh, 1), nl = __shfl_down(ml, 1);
            if (!(jl & 1)) { st4s((int*)H0 + idx, mh | (nh << 16));
                             st4s((int*)H0 + idx + 4, ml | (nl << 16)); }
        }
        split2s(h1v, &sh, &sl);
        {
            int mh = (unsigned short)sh, ml = (unsigned short)sl;
            int nh = __shfl_down(mh, 1), nl = __shfl_down(ml, 1);
            if (!(jl & 1)) { st4s((int*)H1 + idx, mh | (nh << 16));
                             st4s((int*)H1 + idx + 4, ml | (nl << 16)); }
        }
#pragma unroll
        for (int q = 0; q < 4; ++q) {
            bs0[q] = dbih[q*256+j] + dbhh[q*256+j];
            bs1[q] = dbih[GG + q*256+j] + dbhh[GG + q*256+j];
        }
    }

    int lane = tid & 63, w = tid >> 6, cc = lane & 15, g4 = lane >> 4, koff = g4 * 8;
    int tw = w & 1, kb = (w >> 1) * 128;
    int abase = cc * 512 + kb * 2 + g4 * 16;
    int wr = (tw * 16 + cc) * KP + kb + koff;

    short8 xAh[4], xAl[4], xBh[4], xBl[4], h1ih[4], h1il[4];

    // preload: xB := H0[0], h1i := H1[0] (dataflow poll: other blocks' init chunks)
    {
        const short* p0 = H0 + abase;
        const short* p1 = H1 + abase;
        int tries = 0;
        while (true) {
#pragma unroll
            for (int ki = 0; ki < 4; ++ki) {
                xBh[ki] = ld16s(p0 + ki * 64); xBl[ki] = ld16s(p0 + ki * 64 + 8);
                h1ih[ki] = ld16s(p1 + ki * 64); h1il[ki] = ld16s(p1 + ki * 64 + 8);
            }
            vmwait();
            unsigned bad = 0;
#pragma unroll
            for (int ki = 0; ki < 4; ++ki)
                bad |= chk(xBh[ki]) | chk(xBl[ki]) | chk(h1ih[ki]) | chk(h1il[ki]);
            if (!__any((int)bad) || ++tries > MAXTRY) break;
        }
    }

    for (int t = 0; t < TT - 1; ++t) {
        // ---- phase A: layer 0 : x = (t? H1[t] : TE) polled, h = xB regs ----
        {
            const short* px = (t ? H1 + (long)t * SLOT_S : TE) + abase;
            int tries = 0;
            while (true) {
#pragma unroll
                for (int ki = 0; ki < 4; ++ki) {
                    xAh[ki] = ld16s(px + ki * 64); xAl[ki] = ld16s(px + ki * 64 + 8);
                }
                vmwait();
                unsigned bad = 0;
#pragma unroll
                for (int ki = 0; ki < 4; ++ki) bad |= chk(xAh[ki]) | chk(xAl[ki]);
                if (!__any((int)bad) || ++tries > MAXTRY) break;
            }
            f32x4 a1 = {0.f,0.f,0.f,0.f}, a2 = {0.f,0.f,0.f,0.f};
#pragma unroll
            for (int ki = 0; ki < 4; ++ki) {
                a1 = MFMA(xAh[ki], *(const short8*)(Wl[0] + wr + ki * 32), a1);
                a2 = MFMA(xAh[ki], *(const short8*)(Wl[1] + wr + ki * 32), a2);
                a2 = MFMA(xAl[ki], *(const short8*)(Wl[0] + wr + ki * 32), a2);
                a1 = MFMA(xBh[ki], *(const short8*)(Wl[2] + wr + ki * 32), a1);
                a2 = MFMA(xBh[ki], *(const short8*)(Wl[3] + wr + ki * 32), a2);
                a2 = MFMA(xBl[ki], *(const short8*)(Wl[2] + wr + ki * 32), a2);
            }
            f32x4 accs = a1 + a2;
#pragma unroll
            for (int r = 0; r < 4; ++r) gacc[0][w][g4 * 4 + r][cc] = accs[r];
        }
        __syncthreads();
        if (tid < 128) {
            float gv[4];
#pragma unroll
            for (int q = 0; q < 4; ++q) {
                int lr = q * 8 + jl;
                gv[q] = gacc[0][lr >> 4][bb][lr & 15] + gacc[0][2 + (lr >> 4)][bb][lr & 15] + bs0[q];
            }
            float c = sigm(gv[1]) * c0r + sigm(gv[0]) * tanh_f(gv[2]);
            c0r = c;
            float h = sigm(gv[3]) * tanh_f(c);
            short sh, sl; split2s(h, &sh, &sl);
            int mh = (unsigned short)sh, ml = (unsigned short)sl;
            int nh = __shfl_down(mh, 1), nl = __shfl_down(ml, 1);
            if (!(jl & 1)) {
                int idx = bb * 256 + bid * 8 + (jl >> 1);
                int* dst = (int*)(H0 + (long)(t + 1) * SLOT_S);
                st4s(dst + idx, mh | (nh << 16));
                st4s(dst + idx + 4, ml | (nl << 16));
            }
        }
        // ---- phase B: layer 1 : x = H0[t+1] polled, h = (t? xA : h1i) regs ----
        {
            const short* px = H0 + (long)(t + 1) * SLOT_S + abase;
            int tries = 0;
            while (true) {
#pragma unroll
                for (int ki = 0; ki < 4; ++ki) {
                    xBh[ki] = ld16s(px + ki * 64); xBl[ki] = ld16s(px + ki * 64 + 8);
                }
                vmwait();
                unsigned bad = 0;
#pragma unroll
                for (int ki = 0; ki < 4; ++ki) bad |= chk(xBh[ki]) | chk(xBl[ki]);
                if (!__any((int)bad) || ++tries > MAXTRY) break;
            }
            f32x4 a1 = {0.f,0.f,0.f,0.f}, a2 = {0.f,0.f,0.f,0.f};
#pragma unroll
            for (int ki = 0; ki < 4; ++ki) {
                short8 hh = t ? xAh[ki] : h1ih[ki];
                short8 hl = t ? xAl[ki] : h1il[ki];
                a1 = MFMA(xBh[ki], *(const short8*)(Wl[4] + wr + ki * 32), a1);
                a2 = MFMA(xBh[ki], *(const short8*)(Wl[5] + wr + ki * 32), a2);
                a2 = MFMA(xBl[ki], *(const short8*)(Wl[4] + wr + ki * 32), a2);
                a1 = MFMA(hh, *(const short8*)(Wl[6] + wr + ki * 32), a1);
                a2 = MFMA(hh, *(const short8*)(Wl[7] + wr + ki * 32), a2);
                a2 = MFMA(hl, *(const short8*)(Wl[6] + wr + ki * 32), a2);
            }
            f32x4 accs = a1 + a2;
#pragma unroll
            for (int r = 0; r < 4; ++r) gacc[1][w][g4 * 4 + r][cc] = accs[r];
        }
        __syncthreads();
        if (tid < 128) {
            float gv[4];
#pragma unroll
            for (int q = 0; q < 4; ++q) {
                int lr = q * 8 + jl;
                gv[q] = gacc[1][lr >> 4][bb][lr & 15] + gacc[1][2 + (lr >> 4)][bb][lr & 15] + bs1[q];
            }
            float c = sigm(gv[1]) * c1r + sigm(gv[0]) * tanh_f(gv[2]);
            c1r = c;
            float h = sigm(gv[3]) * tanh_f(c);
            short sh, sl; split2s(h, &sh, &sl);
            int mh = (unsigned short)sh, ml = (unsigned short)sl;
            int nh = __shfl_down(mh, 1), nl = __shfl_down(ml, 1);
            if (!(jl & 1)) {
                int idx = bb * 256 + bid * 8 + (jl >> 1);
                int* dst = (int*)(H1 + (long)(t + 1) * SLOT_S);
                st4s(dst + idx, mh | (nh << 16));
                st4s(dst + idx + 4, ml | (nl << 16));
            }
            preds[((long)(t + 1) * BB + bb) * HH + j] = h;
        }
    }
}

// ---------------- host launch ----------------
extern "C" void kernel_launch(void* const* d_in, const int* in_sizes, int n_in,
                              void* d_out, int out_size, void* d_ws, size_t ws_size,
                              hipStream_t stream) {
    const int*   src   = (const int*)  d_in[0];
    const float* te    = (const float*)d_in[2];
    const float* h0    = (const float*)d_in[3];
    const float* c0    = (const float*)d_in[4];
    const float* table = (const float*)d_in[5];
    const float* eWih  = (const float*)d_in[6];
    const float* eWhh  = (const float*)d_in[7];
    const float* ebih  = (const float*)d_in[8];
    const float* ebhh  = (const float*)d_in[9];
    const float* dWih  = (const float*)d_in[10];
    const float* dWhh  = (const float*)d_in[11];
    const float* dbih  = (const float*)d_in[12];
    const float* dbhh  = (const float*)d_in[13];
    float* preds = (float*)d_out;

    const int WN = GG * EE;
    const size_t MB = 1u << 20;
    char* ws = (char*)d_ws;
    short* eWih_hi = (short*)(ws + 0 * MB);
    short* eWih_lo = (short*)(ws + 1 * MB);
    short* eWhh_hi = (short*)(ws + 2 * MB);
    short* eWhh_lo = (short*)(ws + 3 * MB);
    short* dWih_hi = (short*)(ws + 4 * MB);
    short* dWih_lo = (short*)(ws + 5 * MB);
    short* dWhh_hi = (short*)(ws + 6 * MB);
    short* dWhh_lo = (short*)(ws + 7 * MB);
    short* Xa_hi   = (short*)(ws + 8 * MB);
    short* Xa_lo   = (short*)(ws + 10 * MB);
    float* hfin    = (float*)(ws + 12 * MB);
    short* slots   = (short*)(ws + 13 * MB);
    // slot arrays (in shorts): enc H0 257, enc H1 257, dec H0 128, dec H1 128, TE 1
    short* SLe0 = slots;
    short* SLe1 = SLe0 + (long)257 * SLOT_S;
    short* SLd0 = SLe1 + (long)257 * SLOT_S;
    short* SLd1 = SLd0 + (long)128 * SLOT_S;
    short* SLte = SLd1 + (long)128 * SLOT_S;
    float* gates0 = (float*)(ws + 26 * MB);

    const int NSLOT = 257 + 257 + 128 + 128 + 1;   // 771 slots x 16KB
    // sentinel-fill all slots: 771*16384/(256*16) = 3084 blocks
    k_sent<<<3084, 256, 0, stream>>>((unsigned*)slots);

    k_cvt2<<<2048, 256, 0, stream>>>(eWih, (__hip_bfloat16*)eWih_hi, (__hip_bfloat16*)eWih_lo, 2 * WN);
    k_cvt2<<<2048, 256, 0, stream>>>(eWhh, (__hip_bfloat16*)eWhh_hi, (__hip_bfloat16*)eWhh_lo, 2 * WN);
    k_cvt2<<<2048, 256, 0, stream>>>(dWih, (__hip_bfloat16*)dWih_hi, (__hip_bfloat16*)dWih_lo, 2 * WN);
    k_cvt2<<<2048, 256, 0, stream>>>(dWhh, (__hip_bfloat16*)dWhh_hi, (__hip_bfloat16*)dWhh_lo, 2 * WN);

    k_embed<<<4096, 256, 0, stream>>>(src, table, (__hip_bfloat16*)Xa_hi, (__hip_bfloat16*)Xa_lo);
    k_gemm_in<<<4096, 256, 0, stream>>>((__hip_bfloat16*)Xa_hi, (__hip_bfloat16*)Xa_lo,
                                        (__hip_bfloat16*)eWih_hi, (__hip_bfloat16*)eWih_lo,
                                        ebih, ebhh, gates0);
    k_enc_coop<<<NWG, 256, 0, stream>>>(gates0, eWhh_hi, eWhh_lo,
                                        eWih_hi + WN, eWih_lo + WN, eWhh_hi + WN, eWhh_lo + WN,
                                        ebih + GG, ebhh + GG, h0, c0,
                                        SLe0, SLe1, hfin);

    k_dec_coop<<<NWG, 256, 0, stream>>>(dWih_hi, dWih_lo, dWhh_hi, dWhh_lo,
                                        dbih, dbhh, te, hfin,
                                        SLd0, SLd1, SLte, preds);

    k_zero<<<16, 256, 0, stream>>>(preds);
    (void)NSLOT; (void)in_sizes; (void)n_in; (void)out_size; (void)ws_size;
}